// Round 1
// 541.658 us; speedup vs baseline: 1.1240x; 1.1240x over previous
//
#include <hip/hip_runtime.h>
#include <stdint.h>

typedef __bf16 bf16_t;
typedef bf16_t bf16x8 __attribute__((ext_vector_type(8)));
typedef float f32x4 __attribute__((ext_vector_type(4)));
typedef unsigned int u32;
typedef unsigned short u16;

#define DEV_INLINE __device__ __forceinline__

// ---------- constants ----------
#define S_LEN 2048
#define D_MODEL 4096
#define HQ 32
#define HK 8
#define HD 128
#define NQKV 6144   // HQ*HD + 2*HK*HD

DEV_INLINE u16 f2bf(float x) {
  union { float f; uint32_t u; } v; v.f = x;
  uint32_t r = v.u + 0x7FFFu + ((v.u >> 16) & 1u);  // RNE
  return (u16)(r >> 16);
}
DEV_INLINE float bf2f(u16 x) {
  union { uint32_t u; float f; } v; v.u = ((uint32_t)x) << 16;
  return v.f;
}
DEV_INLINE u32 pack2bf(float a, float b) {
  return (u32)f2bf(a) | ((u32)f2bf(b) << 16);
}

DEV_INLINE void async_load16(const void* g, void* l) {
  __builtin_amdgcn_global_load_lds(
      (const __attribute__((address_space(1))) u32*)g,
      (__attribute__((address_space(3))) u32*)l, 16, 0, 0);
}

DEV_INLINE f32x4 mfma16(bf16x8 a, bf16x8 b, f32x4 c) {
  return __builtin_amdgcn_mfma_f32_16x16x32_bf16(a, b, c, 0, 0, 0);
}

// ---------- elementwise f32 -> bf16 ----------
__global__ void cvt_f32_bf16(const float* __restrict__ in, u16* __restrict__ out, int n) {
  int i = (blockIdx.x * blockDim.x + threadIdx.x) * 4;
  if (i >= n) return;
  float4 v = *(const float4*)(in + i);
  union { u16 s[4]; uint2 u; } o;
  o.s[0] = f2bf(v.x); o.s[1] = f2bf(v.y); o.s[2] = f2bf(v.z); o.s[3] = f2bf(v.w);
  *(uint2*)(out + i) = o.u;
}

// ---------- transpose fp32 (R,C) -> bf16 (C,R) ----------
__global__ void transpose_f32_bf16(const float* __restrict__ in, u16* __restrict__ out,
                                   int R, int C) {
  __shared__ float tile[32][33];
  int tx = threadIdx.x, ty = threadIdx.y;           // block (32,8)
  int c0 = blockIdx.x * 32, r0 = blockIdx.y * 32;
#pragma unroll
  for (int i = 0; i < 4; ++i)
    tile[ty + i * 8][tx] = in[(long)(r0 + ty + i * 8) * C + c0 + tx];
  __syncthreads();
#pragma unroll
  for (int i = 0; i < 4; ++i)
    out[(long)(c0 + ty + i * 8) * R + r0 + tx] = f2bf(tile[tx][ty + i * 8]);
}

// ---------- transpose bf16 (R, ld_in cols, slice [col_off, col_off+C)) -> (C, R) ----------
__global__ void transpose_bf16(const u16* __restrict__ in, u16* __restrict__ out,
                               int R, int C, int ld_in, int col_off) {
  __shared__ u16 tile[32][33];
  int tx = threadIdx.x, ty = threadIdx.y;           // block (32,8)
  int c0 = blockIdx.x * 32, r0 = blockIdx.y * 32;
#pragma unroll
  for (int i = 0; i < 4; ++i)
    tile[ty + i * 8][tx] = in[(long)(r0 + ty + i * 8) * ld_in + col_off + c0 + tx];
  __syncthreads();
#pragma unroll
  for (int i = 0; i < 4; ++i)
    out[(long)(c0 + ty + i * 8) * R + r0 + tx] = tile[tx][ty + i * 8];
}

// ---------- RoPE on bf16 (strided input slice) -> packed bf16 ----------
__global__ void rope_bf16(const u16* __restrict__ in, const float* __restrict__ cosb,
                          const float* __restrict__ sinb, u16* __restrict__ out,
                          int H, int ld_in, int col_off, float scale) {
  int idx = blockIdx.x * blockDim.x + threadIdx.x;   // over S*H*64
  int j = idx & 63;
  int sh = idx >> 6;            // s*H + h
  int s = sh / H, h = sh - s * H;
  const u16* ip = in + (long)s * ld_in + col_off + h * HD;
  union { u32 u; u16 s2[2]; } v; v.u = *(const u32*)(ip + 2 * j);
  float q0 = bf2f(v.s2[0]), q1 = bf2f(v.s2[1]);
  float c = cosb[s * 64 + j], sn = sinb[s * 64 + j];
  union { u16 s2[2]; u32 u; } o;
  o.s2[0] = f2bf((q0 * c - q1 * sn) * scale);
  o.s2[1] = f2bf((q0 * sn + q1 * c) * scale);
  *(u32*)(out + (long)sh * HD + 2 * j) = o.u;
}

// ---------- pipelined GEMM: BM=256, BK=32, 4-deep LDS ring, 8 waves ----------
// Tile t lives in ring slot t&3. Stage of tile t issues during tile t-3's phases.
// WAR: slot (t&3) last read by tile t-4, whose reads end at its trailing barrier,
//      strictly before tile t-3 begins -> issue-after-barrier safe.
// RAW: vmcnt(2*LPT) at end of tile t (in-order retirement) guarantees tile t+1
//      fully landed; trailing s_barrier publishes across waves.
// All barriers are inline-asm (no compiler vmcnt(0) drain; "memory" clobber
// pins loads/DMA inside their phase).
#define BARRIER() asm volatile("s_barrier" ::: "memory")
#define WAIT_LGKM0()                                            \
  do {                                                          \
    asm volatile("s_waitcnt lgkmcnt(0)" ::: "memory");          \
    __builtin_amdgcn_sched_barrier(0);                          \
  } while (0)
#define WAIT_VM(N) asm volatile("s_waitcnt vmcnt(" #N ")" ::: "memory")

#define PHASE_A(T, DO_STAGE)                                                      \
  {                                                                               \
    const u16* Ab_ = &lds[(T) & 3][0];                                            \
    const u16* Bb_ = &lds[(T) & 3][8192];                                         \
    bf16x8 af_[MFH];                                                              \
    _Pragma("unroll")                                                             \
    for (int i = 0; i < MFH; ++i) af_[i] = rdfrag(Ab_, wr * MROWS + i * 16 + l15);\
    _Pragma("unroll")                                                             \
    for (int j = 0; j < 4; ++j) bfr[j] = rdfrag(Bb_, wc * 64 + j * 16 + l15);     \
    if (DO_STAGE) stageA((T) + 3);                                                \
    BARRIER();                                                                    \
    WAIT_LGKM0();                                                                 \
    __builtin_amdgcn_s_setprio(1);                                                \
    _Pragma("unroll")                                                             \
    for (int i = 0; i < MFH; ++i)                                                 \
      _Pragma("unroll")                                                           \
      for (int j = 0; j < 4; ++j) acc[i][j] = mfma16(af_[i], bfr[j], acc[i][j]);  \
    __builtin_amdgcn_s_setprio(0);                                                \
    BARRIER();                                                                    \
  }

#define PHASE_B(T, DO_STAGE, VMWAIT)                                              \
  {                                                                               \
    const u16* Ab_ = &lds[(T) & 3][0];                                            \
    bf16x8 af_[MFH];                                                              \
    _Pragma("unroll")                                                             \
    for (int i = 0; i < MFH; ++i)                                                 \
      af_[i] = rdfrag(Ab_, wr * MROWS + (MFH + i) * 16 + l15);                    \
    if (DO_STAGE) stageB((T) + 3);                                                \
    BARRIER();                                                                    \
    WAIT_LGKM0();                                                                 \
    __builtin_amdgcn_s_setprio(1);                                                \
    _Pragma("unroll")                                                             \
    for (int i = 0; i < MFH; ++i)                                                 \
      _Pragma("unroll")                                                           \
      for (int j = 0; j < 4; ++j)                                                 \
        acc[MFH + i][j] = mfma16(af_[i], bfr[j], acc[MFH + i][j]);                \
    __builtin_amdgcn_s_setprio(0);                                                \
    VMWAIT;                                                                       \
    BARRIER();                                                                    \
  }

// C(M,N) = A(M,K)bf16 @ Bt(N,K)^T.  BN=256: waves 2Mx4N (QKV).  BN=128: 4Mx2N (proj).
template <int BN, int WM, bool BF16OUT>
__global__ __launch_bounds__(512, 2) void gemm_pipe(
    const u16* __restrict__ A, const u16* __restrict__ Bt, void* __restrict__ Cv,
    int N, int K) {
  constexpr int WN = 8 / WM;
  constexpr int MROWS = 256 / WM;       // per-wave M rows
  constexpr int MF = MROWS / 16;        // m-frags per wave
  constexpr int MFH = MF / 2;           // m-frags per phase
  constexpr int BPT = (BN * 4) / 512;   // B 16B-chunks per thread (2 or 1)
  constexpr int LDSU = (256 + BN) * 32; // u16 per ring slot

  __shared__ __attribute__((aligned(16))) u16 lds[4][LDSU];

  const int tid = threadIdx.x;
  const int lane = tid & 63;
  const int wave = tid >> 6;
  const int quad = lane >> 4, l15 = lane & 15;
  const int wr = wave / WN, wc = wave % WN;

  // T1: XCD-chunked swizzle (both grids have nwg % 8 == 0)
  const int gx = gridDim.x;
  const int bid = blockIdx.y * gx + blockIdx.x;
  const int cpx = (gx * gridDim.y) >> 3;
  const int sw = (bid & 7) * cpx + (bid >> 3);
  const int bn = sw % gx, bm = sw / gx;

  const long arow = (long)bm * 256, brow = (long)bn * BN;
  const int NT = K >> 5;

  // chunk swizzle: LDS chunk cc of row holds src chunk cc ^ ((row>>1)&3)
  // -> b128 fragment reads hit 8 distinct bank-quads per aligned 8-lane group.
  auto stageA = [&](int ts) {
    const int bs = ts & 3;
    const int k0 = ts * 32;
#pragma unroll
    for (int j = 0; j < 2; ++j) {
      int c = tid + j * 512;
      int row = c >> 2, cc = c & 3, cs = cc ^ ((row >> 1) & 3);
      async_load16(A + (arow + row) * (long)K + k0 + cs * 8,
                   (u16*)&lds[bs][0] + c * 8);
    }
  };
  auto stageB = [&](int ts) {
    const int bs = ts & 3;
    const int k0 = ts * 32;
#pragma unroll
    for (int j = 0; j < BPT; ++j) {
      int c = tid + j * 512;
      int row = c >> 2, cc = c & 3, cs = cc ^ ((row >> 1) & 3);
      async_load16(Bt + (brow + row) * (long)K + k0 + cs * 8,
                   (u16*)&lds[bs][8192] + c * 8);
    }
  };
  auto rdfrag = [&](const u16* base, int row) -> bf16x8 {
    return *(const bf16x8*)(base + row * 32 + ((quad ^ ((row >> 1) & 3)) * 8));
  };

  f32x4 acc[MF][4] = {};
  bf16x8 bfr[4];

  // prologue: stage tiles 0,1,2; drain to tile 0 landed (2 tiles in flight)
  stageA(0); stageB(0); stageA(1); stageB(1); stageA(2); stageB(2);
  if constexpr (BN == 256) { WAIT_VM(8); } else { WAIT_VM(6); }
  BARRIER();

  int t = 0;
  for (; t < NT - 3; ++t) {
    PHASE_A(t, true);
    if constexpr (BN == 256) { PHASE_B(t, true, WAIT_VM(8)); }
    else                     { PHASE_B(t, true, WAIT_VM(6)); }
  }
  // tails: no more staging; tighten waits so tile t+1 is always landed
  PHASE_A(t, false);
  if constexpr (BN == 256) { PHASE_B(t, false, WAIT_VM(4)); }
  else                     { PHASE_B(t, false, WAIT_VM(3)); }
  ++t;
  PHASE_A(t, false);
  PHASE_B(t, false, WAIT_VM(0));
  ++t;
  PHASE_A(t, false);
  PHASE_B(t, false, ((void)0));

  // epilogue: C row from A (quad*4+r), col from B (l15)
#pragma unroll
  for (int i = 0; i < MF; ++i) {
    const long row = (long)bm * 256 + wr * MROWS + i * 16 + quad * 4;
#pragma unroll
    for (int j = 0; j < 4; ++j) {
      const int col = bn * BN + wc * 64 + j * 16 + l15;
      if constexpr (BF16OUT) {
        u16* C = (u16*)Cv;
#pragma unroll
        for (int r = 0; r < 4; ++r) C[(row + r) * N + col] = f2bf(acc[i][j][r]);
      } else {
        float* C = (float*)Cv;
#pragma unroll
        for (int r = 0; r < 4; ++r) C[(row + r) * N + col] = acc[i][j][r];
      }
    }
  }
}

// ---------- flash attention (transposed formulation) ----------
// grid (16, HQ); 256 thr = 4 waves; q-tile 128, wave owns 32 q-rows (2 N-tiles).
// S^T = K @ Q^T (A=kf m->kpos, B=qf n->qrow); O^T = V^T @ P^T (A=vf m->d, B=pf n->qrow).
// P^T round-trips per-wave LDS: b64 writes (4 kpos/lane contiguous) -> b128 reads. No barrier.
// LDS: Ks 32KB + Vs 32KB + Pts 16KB = 80KB -> 2 blocks/CU.
#define NEG_INF -1e30f
__global__ __launch_bounds__(256, 2) void attn_fwd(
    const u16* __restrict__ Qb, const u16* __restrict__ Kb,
    const u16* __restrict__ Vt, u16* __restrict__ Ob) {
  __shared__ __attribute__((aligned(16))) u16 Ks[128 * 128];    // kpos-major
  __shared__ __attribute__((aligned(16))) u16 Vs[128 * 128];    // d-major (V^T)
  __shared__ __attribute__((aligned(16))) u16 Pts[4][16 * 128]; // per-wave P^T (qrow-major)
  const int tid = threadIdx.x;
  const int lane = tid & 63, wave = tid >> 6;
  const int quad = lane >> 4, l15 = lane & 15;
  const int u = 15 - blockIdx.x;        // heavy tiles dispatch first
  const int h = blockIdx.y, hk = h >> 2;
  const int swz = 2 * (l15 & 7);        // even XOR swizzle for Pt groups

  // Q fragments as B-operand: qf[n][ks], n-tile qrow = u*128 + wave*32 + n*16 + l15
  bf16x8 qf[2][4];
#pragma unroll
  for (int n = 0; n < 2; ++n) {
    const u16* qrow = Qb + (long)(u * 128 + wave * 32 + n * 16 + l15) * (HQ * HD)
                      + h * HD + quad * 8;
#pragma unroll
    for (int ks = 0; ks < 4; ++ks) qf[n][ks] = *(const bf16x8*)(qrow + ks * 32);
  }

  float m_run[2] = {NEG_INF, NEG_INF}, l_run[2] = {0.f, 0.f};
  f32x4 oacc[8][2] = {};

  for (int j = 0; j <= u; ++j) {
    // ---- stage K (kpos rows) and V^T (d rows), row&15 XOR swizzle ----
#pragma unroll
    for (int it = 0; it < 8; ++it) {
      int c = tid + it * 256;           // 2048 chunks each
      int row = c >> 4, cc = c & 15, csrc = cc ^ (row & 15);
      async_load16(Kb + (long)(j * 128 + row) * (HK * HD) + hk * HD + csrc * 8,
                   (u16*)Ks + c * 8);
      async_load16(Vt + (long)(hk * HD + row) * S_LEN + j * 128 + csrc * 8,
                   (u16*)Vs + c * 8);
    }
    __syncthreads();

    // ---- S^T = K @ Q^T : sc[tj][n], row=kpos(quad*4+r), col=qrow(l15) ----
    f32x4 sc[8][2] = {};
#pragma unroll
    for (int ks = 0; ks < 4; ++ks)
#pragma unroll
      for (int tj = 0; tj < 8; ++tj) {
        int row = tj * 16 + l15;
        bf16x8 kf = *(const bf16x8*)(Ks + row * 128 + (((ks * 4 + quad) ^ (row & 15)) * 8));
        sc[tj][0] = mfma16(kf, qf[0][ks], sc[tj][0]);
        sc[tj][1] = mfma16(kf, qf[1][ks], sc[tj][1]);
      }

    // ---- online softmax per n (kpos in-lane over tj,r; cross-quad via 2 shuffles) ----
    const bool diag = (j == u);
#pragma unroll
    for (int n = 0; n < 2; ++n) {
      int qloc = wave * 32 + n * 16 + l15;     // local q row within tile
      if (diag) {
#pragma unroll
        for (int tj = 0; tj < 8; ++tj)
#pragma unroll
          for (int r = 0; r < 4; ++r)
            if (tj * 16 + quad * 4 + r > qloc) sc[tj][n][r] = NEG_INF;
      }
      float m = NEG_INF;
#pragma unroll
      for (int tj = 0; tj < 8; ++tj)
#pragma unroll
        for (int r = 0; r < 4; ++r) m = fmaxf(m, sc[tj][n][r]);
      m = fmaxf(m, __shfl_xor(m, 16));
      m = fmaxf(m, __shfl_xor(m, 32));
      float mnew = fmaxf(m_run[n], m);
      float alpha = __expf(m_run[n] - mnew);
      m_run[n] = mnew;
      float rs = 0.f;
#pragma unroll
      for (int tj = 0; tj < 8; ++tj)
#pragma unroll
        for (int r = 0; r < 4; ++r) {
          float p = __expf(sc[tj][n][r] - mnew);
          sc[tj][n][r] = p;
          rs += p;
        }
      rs += __shfl_xor(rs, 16);
      rs += __shfl_xor(rs, 32);
      l_run[n] = l_run[n] * alpha + rs;
#pragma unroll
      for (int tj = 0; tj < 8; ++tj) oacc[tj][n] *= alpha;
    }

    // ---- P^T -> per-wave LDS (b64 writes), read back as B fragments (b128) ----
    u16* pw = &Pts[wave][0];
    bf16x8 pf0[4], pf1[4];
#pragma unroll
    for (int tj = 0; tj < 8; ++tj) {
      union { u32 w[2]; uint2 u2; } pk;
      pk.w[0] = pack2bf(sc[tj][0][0], sc[tj][0][1]);
      pk.w[1] = pack2bf(sc[tj][0][2], sc[tj][0][3]);
      *(uint2*)(pw + l15 * 128 + (((tj * 4 + quad) ^ swz) * 4)) = pk.u2;
    }
    __asm__ volatile("s_waitcnt lgkmcnt(0)" ::: "memory");
#pragma unroll
    for (int ks = 0; ks < 4; ++ks)
      pf0[ks] = *(const bf16x8*)(pw + l15 * 128 + (((ks * 8 + quad * 2) ^ swz) * 4));
    __asm__ volatile("s_waitcnt lgkmcnt(0)" ::: "memory");
#pragma unroll
    for (int tj = 0; tj < 8; ++tj) {
      union { u32 w[2]; uint2 u2; } pk;
      pk.w[0] = pack2bf(sc[tj][1][0], sc[tj][1][1]);
      pk.w[1] = pack2bf(sc[tj][1][2], sc[tj][1][3]);
      *(uint2*)(pw + l15 * 128 + (((tj * 4 + quad) ^ swz) * 4)) = pk.u2;
    }
    __asm__ volatile("s_waitcnt lgkmcnt(0)" ::: "memory");
#pragma unroll
    for (int ks = 0; ks < 4; ++ks)
      pf1[ks] = *(const bf16x8*)(pw + l15 * 128 + (((ks * 8 + quad * 2) ^ swz) * 4));

    // ---- O^T += V^T @ P^T ----
#pragma unroll
    for (int ks = 0; ks < 4; ++ks)
#pragma unroll
      for (int tj = 0; tj < 8; ++tj) {
        int row = tj * 16 + l15;
        bf16x8 vf = *(const bf16x8*)(Vs + row * 128 + (((ks * 4 + quad) ^ (row & 15)) * 8));
        oacc[tj][0] = mfma16(vf, pf0[ks], oacc[tj][0]);
        oacc[tj][1] = mfma16(vf, pf1[ks], oacc[tj][1]);
      }
    __syncthreads();   // all waves done with Ks/Vs before next stage
  }

  // ---- epilogue: O^T tile row=d(quad*4+r), col=qrow(l15); pack 4 bf16 -> 8B store ----
#pragma unroll
  for (int n = 0; n < 2; ++n) {
    float inv_l = 1.0f / l_run[n];
    long grow = u * 128 + wave * 32 + n * 16 + l15;
#pragma unroll
    for (int tj = 0; tj < 8; ++tj) {
      int gcol = h * HD + tj * 16 + quad * 4;
      union { u32 w[2]; uint2 u2; } pk;
      pk.w[0] = pack2bf(oacc[tj][n][0] * inv_l, oacc[tj][n][1] * inv_l);
      pk.w[1] = pack2bf(oacc[tj][n][2] * inv_l, oacc[tj][n][3] * inv_l);
      *(uint2*)(Ob + grow * (HQ * HD) + gcol) = pk.u2;
    }
  }
}

// ---------- host ----------
#define MB (1024L * 1024L)

extern "C" void kernel_launch(void* const* d_in, const int* in_sizes, int n_in,
                              void* d_out, int out_size, void* d_ws, size_t ws_size,
                              hipStream_t stream) {
  const float* x    = (const float*)d_in[0];
  const float* fcos = (const float*)d_in[1];
  const float* fsin = (const float*)d_in[2];
  const float* wq   = (const float*)d_in[3];
  const float* wk   = (const float*)d_in[4];
  const float* wv   = (const float*)d_in[5];
  const float* wo   = (const float*)d_in[6];
  float* out = (float*)d_out;

  char* ws = (char*)d_ws;
  u16* wt    = (u16*)(ws + 0 * MB);     // 48 MB: QKV weights^T (6144,4096); reused for wo^T
  u16* xb    = (u16*)(ws + 48 * MB);    // 16 MB
  u16* QKVb  = (u16*)(ws + 64 * MB);    // 24 MB: (S, 6144) bf16
  u16* Qb    = (u16*)(ws + 88 * MB);    // 16 MB
  u16* Kb    = (u16*)(ws + 104 * MB);   // 4 MB
  u16* Vt    = (u16*)(ws + 108 * MB);   // 4 MB
  u16* attnb = (u16*)(ws + 112 * MB);   // 16 MB

  const int M = S_LEN, D = D_MODEL;

  // x -> bf16
  cvt_f32_bf16<<<(M * D) / 1024, 256, 0, stream>>>(x, xb, M * D);

  // weights^T (concat rows: wq^T | wk^T | wv^T)
  transpose_f32_bf16<<<dim3(D / 32, D / 32), dim3(32, 8), 0, stream>>>(wq, wt, D, HQ * HD);
  transpose_f32_bf16<<<dim3((HK * HD) / 32, D / 32), dim3(32, 8), 0, stream>>>(
      wk, wt + (long)(HQ * HD) * D, D, HK * HD);
  transpose_f32_bf16<<<dim3((HK * HD) / 32, D / 32), dim3(32, 8), 0, stream>>>(
      wv, wt + (long)(HQ * HD + HK * HD) * D, D, HK * HD);

  // fused QKV projection -> bf16  (pipelined 256x256 GEMM, grid 24x8 = 192 wgs)
  gemm_pipe<256, 2, true><<<dim3(NQKV / 256, M / 256), 512, 0, stream>>>(
      xb, wt, QKVb, NQKV, D);

  // RoPE (scale folded into Q) from QKV slices
  rope_bf16<<<(M * HQ * 64) / 256, 256, 0, stream>>>(
      QKVb, fcos, fsin, Qb, HQ, NQKV, 0, 0.08838834764831845f);
  rope_bf16<<<(M * HK * 64) / 256, 256, 0, stream>>>(
      QKVb, fcos, fsin, Kb, HK, NQKV, HQ * HD, 1.0f);
  // V^T from QKV slice
  transpose_bf16<<<dim3((HK * HD) / 32, M / 32), dim3(32, 8), 0, stream>>>(
      QKVb, Vt, M, HK * HD, NQKV, HQ * HD + HK * HD);

  // flash attention
  attn_fwd<<<dim3(16, HQ), 256, 0, stream>>>(Qb, Kb, Vt, attnb);

  // out = attn @ wo  (pipelined 256x128 GEMM, grid 32x8 = 256 wgs = full fill)
  transpose_f32_bf16<<<dim3(D / 32, D / 32), dim3(32, 8), 0, stream>>>(wo, wt, HQ * HD, D);
  gemm_pipe<128, 4, false><<<dim3(D / 128, M / 256), 512, 0, stream>>>(
      attnb, wt, out, D, HQ * HD);
}

// Round 2
// 493.451 us; speedup vs baseline: 1.2338x; 1.0977x over previous
//
#include <hip/hip_runtime.h>
#include <stdint.h>

typedef __bf16 bf16_t;
typedef bf16_t bf16x8 __attribute__((ext_vector_type(8)));
typedef float f32x4 __attribute__((ext_vector_type(4)));
typedef unsigned int u32;
typedef unsigned short u16;

#define DEV_INLINE __device__ __forceinline__

// ---------- constants ----------
#define S_LEN 2048
#define D_MODEL 4096
#define HQ 32
#define HK 8
#define HD 128
#define NQKV 6144   // HQ*HD + 2*HK*HD

DEV_INLINE u16 f2bf(float x) {
  union { float f; uint32_t u; } v; v.f = x;
  uint32_t r = v.u + 0x7FFFu + ((v.u >> 16) & 1u);  // RNE
  return (u16)(r >> 16);
}
DEV_INLINE float bf2f(u16 x) {
  union { uint32_t u; float f; } v; v.u = ((uint32_t)x) << 16;
  return v.f;
}
DEV_INLINE u32 pack2bf(float a, float b) {
  return (u32)f2bf(a) | ((u32)f2bf(b) << 16);
}

DEV_INLINE void async_load16(const void* g, void* l) {
  __builtin_amdgcn_global_load_lds(
      (const __attribute__((address_space(1))) u32*)g,
      (__attribute__((address_space(3))) u32*)l, 16, 0, 0);
}

DEV_INLINE f32x4 mfma16(bf16x8 a, bf16x8 b, f32x4 c) {
  return __builtin_amdgcn_mfma_f32_16x16x32_bf16(a, b, c, 0, 0, 0);
}

// ---------- elementwise f32 -> bf16 ----------
__global__ void cvt_f32_bf16(const float* __restrict__ in, u16* __restrict__ out, int n) {
  int i = (blockIdx.x * blockDim.x + threadIdx.x) * 4;
  if (i >= n) return;
  float4 v = *(const float4*)(in + i);
  union { u16 s[4]; uint2 u; } o;
  o.s[0] = f2bf(v.x); o.s[1] = f2bf(v.y); o.s[2] = f2bf(v.z); o.s[3] = f2bf(v.w);
  *(uint2*)(out + i) = o.u;
}

// ---------- transpose fp32 (R,C) -> bf16 (C,R) ----------
__global__ void transpose_f32_bf16(const float* __restrict__ in, u16* __restrict__ out,
                                   int R, int C) {
  __shared__ float tile[32][33];
  int tx = threadIdx.x, ty = threadIdx.y;           // block (32,8)
  int c0 = blockIdx.x * 32, r0 = blockIdx.y * 32;
#pragma unroll
  for (int i = 0; i < 4; ++i)
    tile[ty + i * 8][tx] = in[(long)(r0 + ty + i * 8) * C + c0 + tx];
  __syncthreads();
#pragma unroll
  for (int i = 0; i < 4; ++i)
    out[(long)(c0 + ty + i * 8) * R + r0 + tx] = f2bf(tile[tx][ty + i * 8]);
}

// ---------- transpose bf16 (R, ld_in cols, slice [col_off, col_off+C)) -> (C, R) ----------
__global__ void transpose_bf16(const u16* __restrict__ in, u16* __restrict__ out,
                               int R, int C, int ld_in, int col_off) {
  __shared__ u16 tile[32][33];
  int tx = threadIdx.x, ty = threadIdx.y;           // block (32,8)
  int c0 = blockIdx.x * 32, r0 = blockIdx.y * 32;
#pragma unroll
  for (int i = 0; i < 4; ++i)
    tile[ty + i * 8][tx] = in[(long)(r0 + ty + i * 8) * ld_in + col_off + c0 + tx];
  __syncthreads();
#pragma unroll
  for (int i = 0; i < 4; ++i)
    out[(long)(c0 + ty + i * 8) * R + r0 + tx] = tile[tx][ty + i * 8];
}

// ---------- RoPE on bf16 (strided input slice) -> packed bf16 ----------
__global__ void rope_bf16(const u16* __restrict__ in, const float* __restrict__ cosb,
                          const float* __restrict__ sinb, u16* __restrict__ out,
                          int H, int ld_in, int col_off, float scale) {
  int idx = blockIdx.x * blockDim.x + threadIdx.x;   // over S*H*64
  int j = idx & 63;
  int sh = idx >> 6;            // s*H + h
  int s = sh / H, h = sh - s * H;
  const u16* ip = in + (long)s * ld_in + col_off + h * HD;
  union { u32 u; u16 s2[2]; } v; v.u = *(const u32*)(ip + 2 * j);
  float q0 = bf2f(v.s2[0]), q1 = bf2f(v.s2[1]);
  float c = cosb[s * 64 + j], sn = sinb[s * 64 + j];
  union { u16 s2[2]; u32 u; } o;
  o.s2[0] = f2bf((q0 * c - q1 * sn) * scale);
  o.s2[1] = f2bf((q0 * sn + q1 * c) * scale);
  *(u32*)(out + (long)sh * HD + 2 * j) = o.u;
}

// ---------- pipelined GEMM: BM=256, BK=32, 4-deep LDS ring, 8 waves ----------
// Tile t lives in ring slot t&3. Stage of tile t issues during tile t-3's phases.
// WAR: slot (t&3) last read by tile t-4, whose reads end at its trailing barrier,
//      strictly before tile t-3 begins -> issue-after-barrier safe.
// RAW: vmcnt(2*LPT) at end of tile t (in-order retirement) guarantees tile t+1
//      fully landed; trailing s_barrier publishes across waves.
// All barriers are inline-asm (no compiler vmcnt(0) drain; "memory" clobber
// pins loads/DMA inside their phase).
#define BARRIER() asm volatile("s_barrier" ::: "memory")
#define WAIT_LGKM0()                                            \
  do {                                                          \
    asm volatile("s_waitcnt lgkmcnt(0)" ::: "memory");          \
    __builtin_amdgcn_sched_barrier(0);                          \
  } while (0)
#define WAIT_VM(N) asm volatile("s_waitcnt vmcnt(" #N ")" ::: "memory")

#define PHASE_A(T, DO_STAGE)                                                      \
  {                                                                               \
    const u16* Ab_ = &lds[(T) & 3][0];                                            \
    const u16* Bb_ = &lds[(T) & 3][8192];                                         \
    bf16x8 af_[MFH];                                                              \
    _Pragma("unroll")                                                             \
    for (int i = 0; i < MFH; ++i) af_[i] = rdfrag(Ab_, wr * MROWS + i * 16 + l15);\
    _Pragma("unroll")                                                             \
    for (int j = 0; j < 4; ++j) bfr[j] = rdfrag(Bb_, wc * 64 + j * 16 + l15);     \
    if (DO_STAGE) stageA((T) + 3);                                                \
    BARRIER();                                                                    \
    WAIT_LGKM0();                                                                 \
    __builtin_amdgcn_s_setprio(1);                                                \
    _Pragma("unroll")                                                             \
    for (int i = 0; i < MFH; ++i)                                                 \
      _Pragma("unroll")                                                           \
      for (int j = 0; j < 4; ++j) acc[i][j] = mfma16(af_[i], bfr[j], acc[i][j]);  \
    __builtin_amdgcn_s_setprio(0);                                                \
    BARRIER();                                                                    \
  }

#define PHASE_B(T, DO_STAGE, VMWAIT)                                              \
  {                                                                               \
    const u16* Ab_ = &lds[(T) & 3][0];                                            \
    bf16x8 af_[MFH];                                                              \
    _Pragma("unroll")                                                             \
    for (int i = 0; i < MFH; ++i)                                                 \
      af_[i] = rdfrag(Ab_, wr * MROWS + (MFH + i) * 16 + l15);                    \
    if (DO_STAGE) stageB((T) + 3);                                                \
    BARRIER();                                                                    \
    WAIT_LGKM0();                                                                 \
    __builtin_amdgcn_s_setprio(1);                                                \
    _Pragma("unroll")                                                             \
    for (int i = 0; i < MFH; ++i)                                                 \
      _Pragma("unroll")                                                           \
      for (int j = 0; j < 4; ++j)                                                 \
        acc[MFH + i][j] = mfma16(af_[i], bfr[j], acc[MFH + i][j]);                \
    __builtin_amdgcn_s_setprio(0);                                                \
    VMWAIT;                                                                       \
    BARRIER();                                                                    \
  }

// C(M,N) = A(M,K)bf16 @ Bt(N,K)^T.  BN=256: waves 2Mx4N (QKV).  BN=128: 4Mx2N (proj).
template <int BN, int WM, bool BF16OUT>
__global__ __launch_bounds__(512, 2) void gemm_pipe(
    const u16* __restrict__ A, const u16* __restrict__ Bt, void* __restrict__ Cv,
    int N, int K) {
  constexpr int WN = 8 / WM;
  constexpr int MROWS = 256 / WM;       // per-wave M rows
  constexpr int MF = MROWS / 16;        // m-frags per wave
  constexpr int MFH = MF / 2;           // m-frags per phase
  constexpr int BPT = (BN * 4) / 512;   // B 16B-chunks per thread (2 or 1)
  constexpr int LDSU = (256 + BN) * 32; // u16 per ring slot

  __shared__ __attribute__((aligned(16))) u16 lds[4][LDSU];

  const int tid = threadIdx.x;
  const int lane = tid & 63;
  const int wave = tid >> 6;
  const int quad = lane >> 4, l15 = lane & 15;
  const int wr = wave / WN, wc = wave % WN;

  // T1: XCD-chunked swizzle (both grids have nwg % 8 == 0)
  const int gx = gridDim.x;
  const int bid = blockIdx.y * gx + blockIdx.x;
  const int cpx = (gx * gridDim.y) >> 3;
  const int sw = (bid & 7) * cpx + (bid >> 3);
  const int bn = sw % gx, bm = sw / gx;

  const long arow = (long)bm * 256, brow = (long)bn * BN;
  const int NT = K >> 5;

  // chunk swizzle: LDS chunk cc of row holds src chunk cc ^ ((row>>1)&3)
  // -> b128 fragment reads hit 8 distinct bank-quads per aligned 8-lane group.
  auto stageA = [&](int ts) {
    const int bs = ts & 3;
    const int k0 = ts * 32;
#pragma unroll
    for (int j = 0; j < 2; ++j) {
      int c = tid + j * 512;
      int row = c >> 2, cc = c & 3, cs = cc ^ ((row >> 1) & 3);
      async_load16(A + (arow + row) * (long)K + k0 + cs * 8,
                   (u16*)&lds[bs][0] + c * 8);
    }
  };
  auto stageB = [&](int ts) {
    const int bs = ts & 3;
    const int k0 = ts * 32;
#pragma unroll
    for (int j = 0; j < BPT; ++j) {
      int c = tid + j * 512;
      int row = c >> 2, cc = c & 3, cs = cc ^ ((row >> 1) & 3);
      async_load16(Bt + (brow + row) * (long)K + k0 + cs * 8,
                   (u16*)&lds[bs][8192] + c * 8);
    }
  };
  auto rdfrag = [&](const u16* base, int row) -> bf16x8 {
    return *(const bf16x8*)(base + row * 32 + ((quad ^ ((row >> 1) & 3)) * 8));
  };

  f32x4 acc[MF][4] = {};
  bf16x8 bfr[4];

  // prologue: stage tiles 0,1,2; drain to tile 0 landed (2 tiles in flight)
  stageA(0); stageB(0); stageA(1); stageB(1); stageA(2); stageB(2);
  if constexpr (BN == 256) { WAIT_VM(8); } else { WAIT_VM(6); }
  BARRIER();

  int t = 0;
  for (; t < NT - 3; ++t) {
    PHASE_A(t, true);
    if constexpr (BN == 256) { PHASE_B(t, true, WAIT_VM(8)); }
    else                     { PHASE_B(t, true, WAIT_VM(6)); }
  }
  // tails: no more staging; tighten waits so tile t+1 is always landed
  PHASE_A(t, false);
  if constexpr (BN == 256) { PHASE_B(t, false, WAIT_VM(4)); }
  else                     { PHASE_B(t, false, WAIT_VM(3)); }
  ++t;
  PHASE_A(t, false);
  PHASE_B(t, false, WAIT_VM(0));
  ++t;
  PHASE_A(t, false);
  PHASE_B(t, false, ((void)0));

  // epilogue: C row from A (quad*4+r), col from B (l15)
#pragma unroll
  for (int i = 0; i < MF; ++i) {
    const long row = (long)bm * 256 + wr * MROWS + i * 16 + quad * 4;
#pragma unroll
    for (int j = 0; j < 4; ++j) {
      const int col = bn * BN + wc * 64 + j * 16 + l15;
      if constexpr (BF16OUT) {
        u16* C = (u16*)Cv;
#pragma unroll
        for (int r = 0; r < 4; ++r) C[(row + r) * N + col] = f2bf(acc[i][j][r]);
      } else {
        float* C = (float*)Cv;
#pragma unroll
        for (int r = 0; r < 4; ++r) C[(row + r) * N + col] = acc[i][j][r];
      }
    }
  }
}

// ---------- flash attention v2 ----------
// grid (16, HQ) = 512 blocks; 256 thr = 4 waves; q-tile 128 (wave owns 32 rows).
// Balanced (h,u) remap: linear b pairs with b+256 on the same CU (round-robin
// heuristic); u(b)+u(b+256)=15 so per-CU work is constant (34 KV-64 iters).
// KVBLK=64, double-buffered K/V; stage(t+1) issued BEFORE compute(t); the
// trailing __syncthreads (vmcnt0+lgkmcnt0+barrier) lands t+1 and republishes.
// WAR safe: buffer (t+1)&1 last read in iter t-1, before its trailing barrier.
// LDS: Ks 2x16KB + Vs 2x16KB + Pts 8KB = 72KB -> 2 blocks/CU.
#define NEG_INF -1e30f
__global__ __launch_bounds__(256, 2) void attn_fwd(
    const u16* __restrict__ Qb, const u16* __restrict__ Kb,
    const u16* __restrict__ Vt, u16* __restrict__ Ob) {
  __shared__ __attribute__((aligned(16))) u16 Ks[2][64 * 128];   // kpos-major
  __shared__ __attribute__((aligned(16))) u16 Vs[2][128 * 64];   // d-major (V^T)
  __shared__ __attribute__((aligned(16))) u16 Pts[4][16 * 64];   // per-wave P^T
  const int tid = threadIdx.x;
  const int lane = tid & 63, wave = tid >> 6;
  const int quad = lane >> 4, l15 = lane & 15;
  const int lin = blockIdx.y * gridDim.x + blockIdx.x;
  const int h = lin & 31;
  const int pp = (lin >> 5) & 7;
  const int u = (lin >> 8) ? 15 - pp : pp;     // q-tile index
  const int hk = h >> 2;
  const int swz = 2 * (l15 & 7);               // even XOR swizzle for Pt units
  const int nt = 2 * (u + 1);                  // KV-64 tiles

  // Q fragments as B-operand: qf[n][ks], qrow = u*128 + wave*32 + n*16 + l15
  bf16x8 qf[2][4];
#pragma unroll
  for (int n = 0; n < 2; ++n) {
    const u16* qrow = Qb + (long)(u * 128 + wave * 32 + n * 16 + l15) * (HQ * HD)
                      + h * HD + quad * 8;
#pragma unroll
    for (int ks = 0; ks < 4; ++ks) qf[n][ks] = *(const bf16x8*)(qrow + ks * 32);
  }

  // stage K (64 kpos rows x 128d, 16 chunks/row, ^row&15) and
  //       V^T (128 d rows x 64 kpos, 8 chunks/row, ^row&7) for tile t
  auto stage = [&](int t) {
    const int b = t & 1;
#pragma unroll
    for (int it = 0; it < 4; ++it) {
      int c = tid + it * 256;
      int row = c >> 4, cc = c & 15, cs = cc ^ (row & 15);
      async_load16(Kb + (long)(t * 64 + row) * (HK * HD) + hk * HD + cs * 8,
                   (u16*)&Ks[b][0] + c * 8);
    }
#pragma unroll
    for (int it = 0; it < 4; ++it) {
      int c = tid + it * 256;
      int row = c >> 3, cc = c & 7, cs = cc ^ (row & 7);
      async_load16(Vt + (long)(hk * HD + row) * S_LEN + t * 64 + cs * 8,
                   (u16*)&Vs[b][0] + c * 8);
    }
  };

  float m_run[2] = {NEG_INF, NEG_INF}, l_run[2] = {0.f, 0.f};
  f32x4 oacc[8][2] = {};

  stage(0);
  __syncthreads();

  for (int t = 0; t < nt; ++t) {
    const int cur = t & 1;
    if (t + 1 < nt) stage(t + 1);

    // skip waves whose rows are entirely above this KV tile (fully masked)
    if (t * 64 <= u * 128 + wave * 32 + 31) {
      // ---- S^T = K @ Q^T : sc[tj][n], row=kpos(quad*4+r), col=qrow(l15) ----
      f32x4 sc[4][2] = {};
      __builtin_amdgcn_s_setprio(1);
#pragma unroll
      for (int ks = 0; ks < 4; ++ks)
#pragma unroll
        for (int tj = 0; tj < 4; ++tj) {
          int row = tj * 16 + l15;
          bf16x8 kf = *(const bf16x8*)(&Ks[cur][0] + row * 128
                                       + (((ks * 4 + quad) ^ (row & 15)) * 8));
          sc[tj][0] = mfma16(kf, qf[0][ks], sc[tj][0]);
          sc[tj][1] = mfma16(kf, qf[1][ks], sc[tj][1]);
        }
      __builtin_amdgcn_s_setprio(0);

      // ---- online softmax (defer-max, THR=8) ----
      const bool diag = (t >= 2 * u);
      const int kbase = t * 64 - u * 128;
#pragma unroll
      for (int n = 0; n < 2; ++n) {
        int qloc = wave * 32 + n * 16 + l15;
        if (diag) {
#pragma unroll
          for (int tj = 0; tj < 4; ++tj)
#pragma unroll
            for (int r = 0; r < 4; ++r)
              if (kbase + tj * 16 + quad * 4 + r > qloc) sc[tj][n][r] = NEG_INF;
        }
        float m = NEG_INF;
#pragma unroll
        for (int tj = 0; tj < 4; ++tj)
#pragma unroll
          for (int r = 0; r < 4; ++r) m = fmaxf(m, sc[tj][n][r]);
        m = fmaxf(m, __shfl_xor(m, 16));
        m = fmaxf(m, __shfl_xor(m, 32));
        if (!__all(m - m_run[n] <= 8.0f)) {
          float mnew = fmaxf(m_run[n], m);
          float alpha = __expf(m_run[n] - mnew);
          m_run[n] = mnew;
          l_run[n] *= alpha;
#pragma unroll
          for (int tj = 0; tj < 8; ++tj) oacc[tj][n] *= alpha;
        }
        float rs = 0.f;
#pragma unroll
        for (int tj = 0; tj < 4; ++tj)
#pragma unroll
          for (int r = 0; r < 4; ++r) {
            float p = __expf(sc[tj][n][r] - m_run[n]);
            sc[tj][n][r] = p;
            rs += p;
          }
        rs += __shfl_xor(rs, 16);
        rs += __shfl_xor(rs, 32);
        l_run[n] += rs;
      }

      // ---- P^T -> per-wave LDS (b64 writes), read back as B frags (b128) ----
      u16* pw = &Pts[wave][0];
      bf16x8 pf0[2], pf1[2];
#pragma unroll
      for (int tj = 0; tj < 4; ++tj) {
        union { u32 w[2]; uint2 u2; } pk;
        pk.w[0] = pack2bf(sc[tj][0][0], sc[tj][0][1]);
        pk.w[1] = pack2bf(sc[tj][0][2], sc[tj][0][3]);
        *(uint2*)(pw + l15 * 64 + (((tj * 4 + quad) ^ swz) * 4)) = pk.u2;
      }
      __asm__ volatile("s_waitcnt lgkmcnt(0)" ::: "memory");
#pragma unroll
      for (int ks = 0; ks < 2; ++ks)
        pf0[ks] = *(const bf16x8*)(pw + l15 * 64 + (((ks * 8 + quad * 2) ^ swz) * 4));
      __asm__ volatile("s_waitcnt lgkmcnt(0)" ::: "memory");
#pragma unroll
      for (int tj = 0; tj < 4; ++tj) {
        union { u32 w[2]; uint2 u2; } pk;
        pk.w[0] = pack2bf(sc[tj][1][0], sc[tj][1][1]);
        pk.w[1] = pack2bf(sc[tj][1][2], sc[tj][1][3]);
        *(uint2*)(pw + l15 * 64 + (((tj * 4 + quad) ^ swz) * 4)) = pk.u2;
      }
      __asm__ volatile("s_waitcnt lgkmcnt(0)" ::: "memory");
#pragma unroll
      for (int ks = 0; ks < 2; ++ks)
        pf1[ks] = *(const bf16x8*)(pw + l15 * 64 + (((ks * 8 + quad * 2) ^ swz) * 4));

      // ---- O^T += V^T @ P^T ----
      __builtin_amdgcn_s_setprio(1);
#pragma unroll
      for (int ks = 0; ks < 2; ++ks)
#pragma unroll
        for (int tj = 0; tj < 8; ++tj) {
          int row = tj * 16 + l15;
          bf16x8 vf = *(const bf16x8*)(&Vs[cur][0] + row * 64
                                       + (((ks * 4 + quad) ^ (row & 7)) * 8));
          oacc[tj][0] = mfma16(vf, pf0[ks], oacc[tj][0]);
          oacc[tj][1] = mfma16(vf, pf1[ks], oacc[tj][1]);
        }
      __builtin_amdgcn_s_setprio(0);
    }

    __syncthreads();   // vmcnt(0): stage(t+1) landed; publishes to all waves
  }

  // ---- epilogue: O^T tile row=d(quad*4+r), col=qrow(l15); pack 4 bf16 ----
#pragma unroll
  for (int n = 0; n < 2; ++n) {
    float inv_l = 1.0f / l_run[n];
    long grow = u * 128 + wave * 32 + n * 16 + l15;
#pragma unroll
    for (int tj = 0; tj < 8; ++tj) {
      int gcol = h * HD + tj * 16 + quad * 4;
      union { u32 w[2]; uint2 u2; } pk;
      pk.w[0] = pack2bf(oacc[tj][n][0] * inv_l, oacc[tj][n][1] * inv_l);
      pk.w[1] = pack2bf(oacc[tj][n][2] * inv_l, oacc[tj][n][3] * inv_l);
      *(uint2*)(Ob + grow * (HQ * HD) + gcol) = pk.u2;
    }
  }
}

// ---------- host ----------
#define MB (1024L * 1024L)

extern "C" void kernel_launch(void* const* d_in, const int* in_sizes, int n_in,
                              void* d_out, int out_size, void* d_ws, size_t ws_size,
                              hipStream_t stream) {
  const float* x    = (const float*)d_in[0];
  const float* fcos = (const float*)d_in[1];
  const float* fsin = (const float*)d_in[2];
  const float* wq   = (const float*)d_in[3];
  const float* wk   = (const float*)d_in[4];
  const float* wv   = (const float*)d_in[5];
  const float* wo   = (const float*)d_in[6];
  float* out = (float*)d_out;

  char* ws = (char*)d_ws;
  u16* wt    = (u16*)(ws + 0 * MB);     // 48 MB: QKV weights^T (6144,4096); reused for wo^T
  u16* xb    = (u16*)(ws + 48 * MB);    // 16 MB
  u16* QKVb  = (u16*)(ws + 64 * MB);    // 24 MB: (S, 6144) bf16
  u16* Qb    = (u16*)(ws + 88 * MB);    // 16 MB
  u16* Kb    = (u16*)(ws + 104 * MB);   // 4 MB
  u16* Vt    = (u16*)(ws + 108 * MB);   // 4 MB
  u16* attnb = (u16*)(ws + 112 * MB);   // 16 MB

  const int M = S_LEN, D = D_MODEL;

  // x -> bf16
  cvt_f32_bf16<<<(M * D) / 1024, 256, 0, stream>>>(x, xb, M * D);

  // weights^T (concat rows: wq^T | wk^T | wv^T)
  transpose_f32_bf16<<<dim3(D / 32, D / 32), dim3(32, 8), 0, stream>>>(wq, wt, D, HQ * HD);
  transpose_f32_bf16<<<dim3((HK * HD) / 32, D / 32), dim3(32, 8), 0, stream>>>(
      wk, wt + (long)(HQ * HD) * D, D, HK * HD);
  transpose_f32_bf16<<<dim3((HK * HD) / 32, D / 32), dim3(32, 8), 0, stream>>>(
      wv, wt + (long)(HQ * HD + HK * HD) * D, D, HK * HD);

  // fused QKV projection -> bf16  (pipelined 256x256 GEMM, grid 24x8 = 192 wgs)
  gemm_pipe<256, 2, true><<<dim3(NQKV / 256, M / 256), 512, 0, stream>>>(
      xb, wt, QKVb, NQKV, D);

  // RoPE (scale folded into Q) from QKV slices
  rope_bf16<<<(M * HQ * 64) / 256, 256, 0, stream>>>(
      QKVb, fcos, fsin, Qb, HQ, NQKV, 0, 0.08838834764831845f);
  rope_bf16<<<(M * HK * 64) / 256, 256, 0, stream>>>(
      QKVb, fcos, fsin, Kb, HK, NQKV, HQ * HD, 1.0f);
  // V^T from QKV slice
  transpose_bf16<<<dim3((HK * HD) / 32, M / 32), dim3(32, 8), 0, stream>>>(
      QKVb, Vt, M, HK * HD, NQKV, HQ * HD + HK * HD);

  // flash attention
  attn_fwd<<<dim3(16, HQ), 256, 0, stream>>>(Qb, Kb, Vt, attnb);

  // out = attn @ wo  (pipelined 256x128 GEMM, grid 32x8 = 256 wgs = full fill)
  transpose_f32_bf16<<<dim3(D / 32, D / 32), dim3(32, 8), 0, stream>>>(wo, wt, HQ * HD, D);
  gemm_pipe<128, 4, false><<<dim3(D / 128, M / 256), 512, 0, stream>>>(
      attnb, wt, out, D, HQ * HD);
}

// Round 3
// 487.757 us; speedup vs baseline: 1.2482x; 1.0117x over previous
//
#include <hip/hip_runtime.h>
#include <stdint.h>

typedef __bf16 bf16_t;
typedef bf16_t bf16x8 __attribute__((ext_vector_type(8)));
typedef float f32x4 __attribute__((ext_vector_type(4)));
typedef unsigned int u32;
typedef unsigned short u16;

#define DEV_INLINE __device__ __forceinline__

// ---------- constants ----------
#define S_LEN 2048
#define D_MODEL 4096
#define HQ 32
#define HK 8
#define HD 128
#define NQKV 6144   // HQ*HD + 2*HK*HD

DEV_INLINE u16 f2bf(float x) {
  union { float f; uint32_t u; } v; v.f = x;
  uint32_t r = v.u + 0x7FFFu + ((v.u >> 16) & 1u);  // RNE
  return (u16)(r >> 16);
}
DEV_INLINE float bf2f(u16 x) {
  union { uint32_t u; float f; } v; v.u = ((uint32_t)x) << 16;
  return v.f;
}
DEV_INLINE u32 pack2bf(float a, float b) {
  return (u32)f2bf(a) | ((u32)f2bf(b) << 16);
}

DEV_INLINE void async_load16(const void* g, void* l) {
  __builtin_amdgcn_global_load_lds(
      (const __attribute__((address_space(1))) u32*)g,
      (__attribute__((address_space(3))) u32*)l, 16, 0, 0);
}

DEV_INLINE f32x4 mfma16(bf16x8 a, bf16x8 b, f32x4 c) {
  return __builtin_amdgcn_mfma_f32_16x16x32_bf16(a, b, c, 0, 0, 0);
}

// ---------- elementwise f32 -> bf16 ----------
__global__ void cvt_f32_bf16(const float* __restrict__ in, u16* __restrict__ out, int n) {
  int i = (blockIdx.x * blockDim.x + threadIdx.x) * 4;
  if (i >= n) return;
  float4 v = *(const float4*)(in + i);
  union { u16 s[4]; uint2 u; } o;
  o.s[0] = f2bf(v.x); o.s[1] = f2bf(v.y); o.s[2] = f2bf(v.z); o.s[3] = f2bf(v.w);
  *(uint2*)(out + i) = o.u;
}

// ---------- transpose fp32 (R,C) -> bf16 (C,R) ----------
__global__ void transpose_f32_bf16(const float* __restrict__ in, u16* __restrict__ out,
                                   int R, int C) {
  __shared__ float tile[32][33];
  int tx = threadIdx.x, ty = threadIdx.y;           // block (32,8)
  int c0 = blockIdx.x * 32, r0 = blockIdx.y * 32;
#pragma unroll
  for (int i = 0; i < 4; ++i)
    tile[ty + i * 8][tx] = in[(long)(r0 + ty + i * 8) * C + c0 + tx];
  __syncthreads();
#pragma unroll
  for (int i = 0; i < 4; ++i)
    out[(long)(c0 + ty + i * 8) * R + r0 + tx] = f2bf(tile[tx][ty + i * 8]);
}

// ---------- transpose bf16 (R, ld_in cols, slice [col_off, col_off+C)) -> (C, R) ----------
__global__ void transpose_bf16(const u16* __restrict__ in, u16* __restrict__ out,
                               int R, int C, int ld_in, int col_off) {
  __shared__ u16 tile[32][33];
  int tx = threadIdx.x, ty = threadIdx.y;           // block (32,8)
  int c0 = blockIdx.x * 32, r0 = blockIdx.y * 32;
#pragma unroll
  for (int i = 0; i < 4; ++i)
    tile[ty + i * 8][tx] = in[(long)(r0 + ty + i * 8) * ld_in + col_off + c0 + tx];
  __syncthreads();
#pragma unroll
  for (int i = 0; i < 4; ++i)
    out[(long)(c0 + ty + i * 8) * R + r0 + tx] = tile[tx][ty + i * 8];
}

// ---------- RoPE on bf16 (strided input slice) -> packed bf16 ----------
__global__ void rope_bf16(const u16* __restrict__ in, const float* __restrict__ cosb,
                          const float* __restrict__ sinb, u16* __restrict__ out,
                          int H, int ld_in, int col_off, float scale) {
  int idx = blockIdx.x * blockDim.x + threadIdx.x;   // over S*H*64
  int j = idx & 63;
  int sh = idx >> 6;            // s*H + h
  int s = sh / H, h = sh - s * H;
  const u16* ip = in + (long)s * ld_in + col_off + h * HD;
  union { u32 u; u16 s2[2]; } v; v.u = *(const u32*)(ip + 2 * j);
  float q0 = bf2f(v.s2[0]), q1 = bf2f(v.s2[1]);
  float c = cosb[s * 64 + j], sn = sinb[s * 64 + j];
  union { u16 s2[2]; u32 u; } o;
  o.s2[0] = f2bf((q0 * c - q1 * sn) * scale);
  o.s2[1] = f2bf((q0 * sn + q1 * c) * scale);
  *(u32*)(out + (long)sh * HD + 2 * j) = o.u;
}

// ---------- pipelined GEMM: BM=256, BK=32, 4-deep LDS ring, 8 waves ----------
// Tile t lives in ring slot t&3. Stage of tile t issues during tile t-3's phases.
// WAR: slot (t&3) last read by tile t-4, whose reads complete (consumed by MFMA)
//      before its trailing barrier, strictly before tile t-3 begins.
// RAW: vmcnt(2*LPT) at end of tile t (in-order retirement) guarantees tile t+1
//      fully landed; trailing s_barrier publishes across waves.
// No forced lgkmcnt(0): ds_read -> MFMA is a register dep, the compiler emits
// fine-grained lgkmcnt(N) interleaving read completion with the MFMA burst.
// Barriers are inline-asm ("memory" clobber pins memory ops inside phases,
// and avoids the compiler's vmcnt(0) drain at __syncthreads).
#define BARRIER() asm volatile("s_barrier" ::: "memory")
#define WAIT_VM(N) asm volatile("s_waitcnt vmcnt(" #N ")" ::: "memory")

#define PHASE_A(T, DO_STAGE)                                                      \
  {                                                                               \
    const u16* Ab_ = &lds[(T) & 3][0];                                            \
    const u16* Bb_ = &lds[(T) & 3][8192];                                         \
    bf16x8 af_[MFH];                                                              \
    _Pragma("unroll")                                                             \
    for (int i = 0; i < MFH; ++i) af_[i] = rdfrag(Ab_, wr * MROWS + i * 16 + l15);\
    _Pragma("unroll")                                                             \
    for (int j = 0; j < NF; ++j) bfr[j] = rdfrag(Bb_, wc * WCOLS + j * 16 + l15); \
    if (DO_STAGE) stageA((T) + 3);                                                \
    BARRIER();                                                                    \
    __builtin_amdgcn_s_setprio(1);                                                \
    _Pragma("unroll")                                                             \
    for (int i = 0; i < MFH; ++i)                                                 \
      _Pragma("unroll")                                                           \
      for (int j = 0; j < NF; ++j) acc[i][j] = mfma16(af_[i], bfr[j], acc[i][j]); \
    __builtin_amdgcn_s_setprio(0);                                                \
    BARRIER();                                                                    \
  }

#define PHASE_B(T, DO_STAGE, VMWAIT)                                              \
  {                                                                               \
    const u16* Ab_ = &lds[(T) & 3][0];                                            \
    bf16x8 af_[MFH];                                                              \
    _Pragma("unroll")                                                             \
    for (int i = 0; i < MFH; ++i)                                                 \
      af_[i] = rdfrag(Ab_, wr * MROWS + (MFH + i) * 16 + l15);                    \
    if (DO_STAGE) stageB((T) + 3);                                                \
    BARRIER();                                                                    \
    __builtin_amdgcn_s_setprio(1);                                                \
    _Pragma("unroll")                                                             \
    for (int i = 0; i < MFH; ++i)                                                 \
      _Pragma("unroll")                                                           \
      for (int j = 0; j < NF; ++j)                                                \
        acc[MFH + i][j] = mfma16(af_[i], bfr[j], acc[MFH + i][j]);                \
    __builtin_amdgcn_s_setprio(0);                                                \
    VMWAIT;                                                                       \
    BARRIER();                                                                    \
  }

// C(M,N) = A(M,K)bf16 @ Bt(N,K)^T.
// BN=192: waves 2Mx4N, per-wave 128x48 (QKV, grid 32x8 = 256 wgs = full fill).
// BN=128: waves 4Mx2N, per-wave 64x64  (proj, grid 32x8 = 256 wgs).
template <int BN, int WM, bool BF16OUT>
__global__ __launch_bounds__(512, 2) void gemm_pipe(
    const u16* __restrict__ A, const u16* __restrict__ Bt, void* __restrict__ Cv,
    int N, int K) {
  constexpr int WN = 8 / WM;
  constexpr int MROWS = 256 / WM;       // per-wave M rows
  constexpr int MF = MROWS / 16;        // m-frags per wave
  constexpr int MFH = MF / 2;           // m-frags per phase
  constexpr int NF = BN / (WN * 16);    // n-frags per wave
  constexpr int WCOLS = NF * 16;        // per-wave N cols
  constexpr int BCH = BN * 4;           // real B 16B-chunks per tile
  constexpr int BISS = (BCH + 511) / 512;   // B loads per thread (w/ dup pad)
  constexpr int LDSU = (256 + BN) * 32; // u16 per ring slot

  __shared__ __attribute__((aligned(16))) u16 lds[4][LDSU];

  const int tid = threadIdx.x;
  const int lane = tid & 63;
  const int wave = tid >> 6;
  const int quad = lane >> 4, l15 = lane & 15;
  const int wr = wave / WN, wc = wave % WN;

  // T1: XCD-chunked swizzle (grid 256 = 8 XCDs x 32; bm = bid&7 -> one A-panel
  // (2 MB) resident per XCD L2)
  const int gx = gridDim.x;
  const int bid = blockIdx.y * gx + blockIdx.x;
  const int cpx = (gx * gridDim.y) >> 3;
  const int sw = (bid & 7) * cpx + (bid >> 3);
  const int bn = sw % gx, bm = sw / gx;

  const long arow = (long)bm * 256, brow = (long)bn * BN;
  const int NT = K >> 5;

  // chunk swizzle: LDS chunk cc of row holds src chunk cc ^ ((row>>1)&3)
  auto stageA = [&](int ts) {
    const int bs = ts & 3;
    const int k0 = ts * 32;
#pragma unroll
    for (int j = 0; j < 2; ++j) {
      int c = tid + j * 512;
      int row = c >> 2, cc = c & 3, cs = cc ^ ((row >> 1) & 3);
      async_load16(A + (arow + row) * (long)K + k0 + cs * 8,
                   (u16*)&lds[bs][0] + c * 8);
    }
  };
  // BN=192: chunks 512..767 are loaded twice (tid and tid+256) to the same LDS
  // dest with the same global data -> benign duplicate; keeps per-wave VMEM
  // issue count uniform so the vmcnt constants hold for every wave.
  auto stageB = [&](int ts) {
    const int bs = ts & 3;
    const int k0 = ts * 32;
#pragma unroll
    for (int j = 0; j < BISS; ++j) {
      int c = tid + j * 512;
      int cd = (c < BCH) ? c : c - 256;
      int row = cd >> 2, cc = cd & 3, cs = cc ^ ((row >> 1) & 3);
      async_load16(Bt + (brow + row) * (long)K + k0 + cs * 8,
                   (u16*)&lds[bs][8192] + cd * 8);
    }
  };
  auto rdfrag = [&](const u16* base, int row) -> bf16x8 {
    return *(const bf16x8*)(base + row * 32 + ((quad ^ ((row >> 1) & 3)) * 8));
  };

  f32x4 acc[MF][NF] = {};
  bf16x8 bfr[NF];

  // prologue: stage tiles 0,1,2; drain so tile 0 landed (2 tiles in flight)
  stageA(0); stageB(0); stageA(1); stageB(1); stageA(2); stageB(2);
  if constexpr (BISS == 2) { WAIT_VM(8); } else { WAIT_VM(6); }
  BARRIER();

  int t = 0;
  for (; t < NT - 3; ++t) {
    PHASE_A(t, true);
    if constexpr (BISS == 2) { PHASE_B(t, true, WAIT_VM(8)); }
    else                     { PHASE_B(t, true, WAIT_VM(6)); }
  }
  // tails: no more staging; tighten waits so tile t+1 is always landed
  PHASE_A(t, false);
  if constexpr (BISS == 2) { PHASE_B(t, false, WAIT_VM(4)); }
  else                     { PHASE_B(t, false, WAIT_VM(3)); }
  ++t;
  PHASE_A(t, false);
  PHASE_B(t, false, WAIT_VM(0));
  ++t;
  PHASE_A(t, false);
  PHASE_B(t, false, ((void)0));

  // epilogue: C row from A (quad*4+r), col from B (l15)
#pragma unroll
  for (int i = 0; i < MF; ++i) {
    const long row = (long)bm * 256 + wr * MROWS + i * 16 + quad * 4;
#pragma unroll
    for (int j = 0; j < NF; ++j) {
      const int col = bn * BN + wc * WCOLS + j * 16 + l15;
      if constexpr (BF16OUT) {
        u16* C = (u16*)Cv;
#pragma unroll
        for (int r = 0; r < 4; ++r) C[(row + r) * N + col] = f2bf(acc[i][j][r]);
      } else {
        float* C = (float*)Cv;
#pragma unroll
        for (int r = 0; r < 4; ++r) C[(row + r) * N + col] = acc[i][j][r];
      }
    }
  }
}

// ---------- flash attention v2 ----------
// grid (16, HQ) = 512 blocks; 256 thr = 4 waves; q-tile 128 (wave owns 32 rows).
// Balanced (h,u) remap: linear b pairs with b+256 on the same CU (round-robin
// heuristic); u(b)+u(b+256)=15 so per-CU work is constant (34 KV-64 iters).
// KVBLK=64, double-buffered K/V; stage(t+1) issued BEFORE compute(t); the
// trailing __syncthreads (vmcnt0+lgkmcnt0+barrier) lands t+1 and republishes.
// WAR safe: buffer (t+1)&1 last read in iter t-1, before its trailing barrier.
// LDS: Ks 2x16KB + Vs 2x16KB + Pts 8KB = 72KB -> 2 blocks/CU.
#define NEG_INF -1e30f
__global__ __launch_bounds__(256, 2) void attn_fwd(
    const u16* __restrict__ Qb, const u16* __restrict__ Kb,
    const u16* __restrict__ Vt, u16* __restrict__ Ob) {
  __shared__ __attribute__((aligned(16))) u16 Ks[2][64 * 128];   // kpos-major
  __shared__ __attribute__((aligned(16))) u16 Vs[2][128 * 64];   // d-major (V^T)
  __shared__ __attribute__((aligned(16))) u16 Pts[4][16 * 64];   // per-wave P^T
  const int tid = threadIdx.x;
  const int lane = tid & 63, wave = tid >> 6;
  const int quad = lane >> 4, l15 = lane & 15;
  const int lin = blockIdx.y * gridDim.x + blockIdx.x;
  const int h = lin & 31;
  const int pp = (lin >> 5) & 7;
  const int u = (lin >> 8) ? 15 - pp : pp;     // q-tile index
  const int hk = h >> 2;
  const int swz = 2 * (l15 & 7);               // even XOR swizzle for Pt units
  const int nt = 2 * (u + 1);                  // KV-64 tiles

  // Q fragments as B-operand: qf[n][ks], qrow = u*128 + wave*32 + n*16 + l15
  bf16x8 qf[2][4];
#pragma unroll
  for (int n = 0; n < 2; ++n) {
    const u16* qrow = Qb + (long)(u * 128 + wave * 32 + n * 16 + l15) * (HQ * HD)
                      + h * HD + quad * 8;
#pragma unroll
    for (int ks = 0; ks < 4; ++ks) qf[n][ks] = *(const bf16x8*)(qrow + ks * 32);
  }

  // stage K (64 kpos rows x 128d, 16 chunks/row, ^row&15) and
  //       V^T (128 d rows x 64 kpos, 8 chunks/row, ^row&7) for tile t
  auto stage = [&](int t) {
    const int b = t & 1;
#pragma unroll
    for (int it = 0; it < 4; ++it) {
      int c = tid + it * 256;
      int row = c >> 4, cc = c & 15, cs = cc ^ (row & 15);
      async_load16(Kb + (long)(t * 64 + row) * (HK * HD) + hk * HD + cs * 8,
                   (u16*)&Ks[b][0] + c * 8);
    }
#pragma unroll
    for (int it = 0; it < 4; ++it) {
      int c = tid + it * 256;
      int row = c >> 3, cc = c & 7, cs = cc ^ (row & 7);
      async_load16(Vt + (long)(hk * HD + row) * S_LEN + t * 64 + cs * 8,
                   (u16*)&Vs[b][0] + c * 8);
    }
  };

  float m_run[2] = {NEG_INF, NEG_INF}, l_run[2] = {0.f, 0.f};
  f32x4 oacc[8][2] = {};

  stage(0);
  __syncthreads();

  for (int t = 0; t < nt; ++t) {
    const int cur = t & 1;
    if (t + 1 < nt) stage(t + 1);

    // skip waves whose rows are entirely above this KV tile (fully masked)
    if (t * 64 <= u * 128 + wave * 32 + 31) {
      // ---- S^T = K @ Q^T : sc[tj][n], row=kpos(quad*4+r), col=qrow(l15) ----
      f32x4 sc[4][2] = {};
      __builtin_amdgcn_s_setprio(1);
#pragma unroll
      for (int ks = 0; ks < 4; ++ks)
#pragma unroll
        for (int tj = 0; tj < 4; ++tj) {
          int row = tj * 16 + l15;
          bf16x8 kf = *(const bf16x8*)(&Ks[cur][0] + row * 128
                                       + (((ks * 4 + quad) ^ (row & 15)) * 8));
          sc[tj][0] = mfma16(kf, qf[0][ks], sc[tj][0]);
          sc[tj][1] = mfma16(kf, qf[1][ks], sc[tj][1]);
        }
      __builtin_amdgcn_s_setprio(0);

      // ---- online softmax (defer-max, THR=8) ----
      const bool diag = (t >= 2 * u);
      const int kbase = t * 64 - u * 128;
#pragma unroll
      for (int n = 0; n < 2; ++n) {
        int qloc = wave * 32 + n * 16 + l15;
        if (diag) {
#pragma unroll
          for (int tj = 0; tj < 4; ++tj)
#pragma unroll
            for (int r = 0; r < 4; ++r)
              if (kbase + tj * 16 + quad * 4 + r > qloc) sc[tj][n][r] = NEG_INF;
        }
        float m = NEG_INF;
#pragma unroll
        for (int tj = 0; tj < 4; ++tj)
#pragma unroll
          for (int r = 0; r < 4; ++r) m = fmaxf(m, sc[tj][n][r]);
        m = fmaxf(m, __shfl_xor(m, 16));
        m = fmaxf(m, __shfl_xor(m, 32));
        if (!__all(m - m_run[n] <= 8.0f)) {
          float mnew = fmaxf(m_run[n], m);
          float alpha = __expf(m_run[n] - mnew);
          m_run[n] = mnew;
          l_run[n] *= alpha;
#pragma unroll
          for (int tj = 0; tj < 8; ++tj) oacc[tj][n] *= alpha;
        }
        float rs = 0.f;
#pragma unroll
        for (int tj = 0; tj < 4; ++tj)
#pragma unroll
          for (int r = 0; r < 4; ++r) {
            float p = __expf(sc[tj][n][r] - m_run[n]);
            sc[tj][n][r] = p;
            rs += p;
          }
        rs += __shfl_xor(rs, 16);
        rs += __shfl_xor(rs, 32);
        l_run[n] += rs;
      }

      // ---- P^T -> per-wave LDS (b64 writes), read back as B frags (b128) ----
      u16* pw = &Pts[wave][0];
      bf16x8 pf0[2], pf1[2];
#pragma unroll
      for (int tj = 0; tj < 4; ++tj) {
        union { u32 w[2]; uint2 u2; } pk;
        pk.w[0] = pack2bf(sc[tj][0][0], sc[tj][0][1]);
        pk.w[1] = pack2bf(sc[tj][0][2], sc[tj][0][3]);
        *(uint2*)(pw + l15 * 64 + (((tj * 4 + quad) ^ swz) * 4)) = pk.u2;
      }
      __asm__ volatile("s_waitcnt lgkmcnt(0)" ::: "memory");
#pragma unroll
      for (int ks = 0; ks < 2; ++ks)
        pf0[ks] = *(const bf16x8*)(pw + l15 * 64 + (((ks * 8 + quad * 2) ^ swz) * 4));
      __asm__ volatile("s_waitcnt lgkmcnt(0)" ::: "memory");
#pragma unroll
      for (int tj = 0; tj < 4; ++tj) {
        union { u32 w[2]; uint2 u2; } pk;
        pk.w[0] = pack2bf(sc[tj][1][0], sc[tj][1][1]);
        pk.w[1] = pack2bf(sc[tj][1][2], sc[tj][1][3]);
        *(uint2*)(pw + l15 * 64 + (((tj * 4 + quad) ^ swz) * 4)) = pk.u2;
      }
      __asm__ volatile("s_waitcnt lgkmcnt(0)" ::: "memory");
#pragma unroll
      for (int ks = 0; ks < 2; ++ks)
        pf1[ks] = *(const bf16x8*)(pw + l15 * 64 + (((ks * 8 + quad * 2) ^ swz) * 4));

      // ---- O^T += V^T @ P^T ----
      __builtin_amdgcn_s_setprio(1);
#pragma unroll
      for (int ks = 0; ks < 2; ++ks)
#pragma unroll
        for (int tj = 0; tj < 8; ++tj) {
          int row = tj * 16 + l15;
          bf16x8 vf = *(const bf16x8*)(&Vs[cur][0] + row * 64
                                       + (((ks * 4 + quad) ^ (row & 7)) * 8));
          oacc[tj][0] = mfma16(vf, pf0[ks], oacc[tj][0]);
          oacc[tj][1] = mfma16(vf, pf1[ks], oacc[tj][1]);
        }
      __builtin_amdgcn_s_setprio(0);
    }

    __syncthreads();   // vmcnt(0): stage(t+1) landed; publishes to all waves
  }

  // ---- epilogue: O^T tile row=d(quad*4+r), col=qrow(l15); pack 4 bf16 ----
#pragma unroll
  for (int n = 0; n < 2; ++n) {
    float inv_l = 1.0f / l_run[n];
    long grow = u * 128 + wave * 32 + n * 16 + l15;
#pragma unroll
    for (int tj = 0; tj < 8; ++tj) {
      int gcol = h * HD + tj * 16 + quad * 4;
      union { u32 w[2]; uint2 u2; } pk;
      pk.w[0] = pack2bf(oacc[tj][n][0] * inv_l, oacc[tj][n][1] * inv_l);
      pk.w[1] = pack2bf(oacc[tj][n][2] * inv_l, oacc[tj][n][3] * inv_l);
      *(uint2*)(Ob + grow * (HQ * HD) + gcol) = pk.u2;
    }
  }
}

// ---------- host ----------
#define MB (1024L * 1024L)

extern "C" void kernel_launch(void* const* d_in, const int* in_sizes, int n_in,
                              void* d_out, int out_size, void* d_ws, size_t ws_size,
                              hipStream_t stream) {
  const float* x    = (const float*)d_in[0];
  const float* fcos = (const float*)d_in[1];
  const float* fsin = (const float*)d_in[2];
  const float* wq   = (const float*)d_in[3];
  const float* wk   = (const float*)d_in[4];
  const float* wv   = (const float*)d_in[5];
  const float* wo   = (const float*)d_in[6];
  float* out = (float*)d_out;

  char* ws = (char*)d_ws;
  u16* wt    = (u16*)(ws + 0 * MB);     // 48 MB: QKV weights^T (6144,4096); reused for wo^T
  u16* xb    = (u16*)(ws + 48 * MB);    // 16 MB
  u16* QKVb  = (u16*)(ws + 64 * MB);    // 24 MB: (S, 6144) bf16
  u16* Qb    = (u16*)(ws + 88 * MB);    // 16 MB
  u16* Kb    = (u16*)(ws + 104 * MB);   // 4 MB
  u16* Vt    = (u16*)(ws + 108 * MB);   // 4 MB
  u16* attnb = (u16*)(ws + 112 * MB);   // 16 MB

  const int M = S_LEN, D = D_MODEL;

  // x -> bf16
  cvt_f32_bf16<<<(M * D) / 1024, 256, 0, stream>>>(x, xb, M * D);

  // weights^T (concat rows: wq^T | wk^T | wv^T)
  transpose_f32_bf16<<<dim3(D / 32, D / 32), dim3(32, 8), 0, stream>>>(wq, wt, D, HQ * HD);
  transpose_f32_bf16<<<dim3((HK * HD) / 32, D / 32), dim3(32, 8), 0, stream>>>(
      wk, wt + (long)(HQ * HD) * D, D, HK * HD);
  transpose_f32_bf16<<<dim3((HK * HD) / 32, D / 32), dim3(32, 8), 0, stream>>>(
      wv, wt + (long)(HQ * HD + HK * HD) * D, D, HK * HD);

  // fused QKV projection -> bf16  (pipelined 256x192 GEMM, grid 32x8 = 256 wgs)
  gemm_pipe<192, 2, true><<<dim3(NQKV / 192, M / 256), 512, 0, stream>>>(
      xb, wt, QKVb, NQKV, D);

  // RoPE (scale folded into Q) from QKV slices
  rope_bf16<<<(M * HQ * 64) / 256, 256, 0, stream>>>(
      QKVb, fcos, fsin, Qb, HQ, NQKV, 0, 0.08838834764831845f);
  rope_bf16<<<(M * HK * 64) / 256, 256, 0, stream>>>(
      QKVb, fcos, fsin, Kb, HK, NQKV, HQ * HD, 1.0f);
  // V^T from QKV slice
  transpose_bf16<<<dim3((HK * HD) / 32, M / 32), dim3(32, 8), 0, stream>>>(
      QKVb, Vt, M, HK * HD, NQKV, HQ * HD + HK * HD);

  // flash attention
  attn_fwd<<<dim3(16, HQ), 256, 0, stream>>>(Qb, Kb, Vt, attnb);

  // out = attn @ wo  (pipelined 256x128 GEMM, grid 32x8 = 256 wgs)
  transpose_f32_bf16<<<dim3(D / 32, D / 32), dim3(32, 8), 0, stream>>>(wo, wt, HQ * HD, D);
  gemm_pipe<128, 4, false><<<dim3(D / 128, M / 256), 512, 0, stream>>>(
      attnb, wt, out, D, HQ * HD);
}

// Round 4
// 478.271 us; speedup vs baseline: 1.2729x; 1.0198x over previous
//
#include <hip/hip_runtime.h>
#include <stdint.h>

typedef __bf16 bf16_t;
typedef bf16_t bf16x8 __attribute__((ext_vector_type(8)));
typedef float f32x4 __attribute__((ext_vector_type(4)));
typedef unsigned int u32;
typedef unsigned short u16;

#define DEV_INLINE __device__ __forceinline__

// ---------- constants ----------
#define S_LEN 2048
#define D_MODEL 4096
#define HQ 32
#define HK 8
#define HD 128
#define NQKV 6144   // HQ*HD + 2*HK*HD

DEV_INLINE u16 f2bf(float x) {
  union { float f; uint32_t u; } v; v.f = x;
  uint32_t r = v.u + 0x7FFFu + ((v.u >> 16) & 1u);  // RNE
  return (u16)(r >> 16);
}
DEV_INLINE float bf2f(u16 x) {
  union { uint32_t u; float f; } v; v.u = ((uint32_t)x) << 16;
  return v.f;
}
DEV_INLINE u32 pack2bf(float a, float b) {
  return (u32)f2bf(a) | ((u32)f2bf(b) << 16);
}

DEV_INLINE void async_load16(const void* g, void* l) {
  __builtin_amdgcn_global_load_lds(
      (const __attribute__((address_space(1))) u32*)g,
      (__attribute__((address_space(3))) u32*)l, 16, 0, 0);
}

DEV_INLINE f32x4 mfma16(bf16x8 a, bf16x8 b, f32x4 c) {
  return __builtin_amdgcn_mfma_f32_16x16x32_bf16(a, b, c, 0, 0, 0);
}

// ---------- elementwise f32 -> bf16 ----------
__global__ void cvt_f32_bf16(const float* __restrict__ in, u16* __restrict__ out, int n) {
  int i = (blockIdx.x * blockDim.x + threadIdx.x) * 4;
  if (i >= n) return;
  float4 v = *(const float4*)(in + i);
  union { u16 s[4]; uint2 u; } o;
  o.s[0] = f2bf(v.x); o.s[1] = f2bf(v.y); o.s[2] = f2bf(v.z); o.s[3] = f2bf(v.w);
  *(uint2*)(out + i) = o.u;
}

// ---------- transpose fp32 (R,C) -> bf16 (C,R) ----------
__global__ void transpose_f32_bf16(const float* __restrict__ in, u16* __restrict__ out,
                                   int R, int C) {
  __shared__ float tile[32][33];
  int tx = threadIdx.x, ty = threadIdx.y;           // block (32,8)
  int c0 = blockIdx.x * 32, r0 = blockIdx.y * 32;
#pragma unroll
  for (int i = 0; i < 4; ++i)
    tile[ty + i * 8][tx] = in[(long)(r0 + ty + i * 8) * C + c0 + tx];
  __syncthreads();
#pragma unroll
  for (int i = 0; i < 4; ++i)
    out[(long)(c0 + ty + i * 8) * R + r0 + tx] = f2bf(tile[tx][ty + i * 8]);
}

// ---------- transpose bf16 (R, ld_in cols, slice [col_off, col_off+C)) -> (C, R) ----------
__global__ void transpose_bf16(const u16* __restrict__ in, u16* __restrict__ out,
                               int R, int C, int ld_in, int col_off) {
  __shared__ u16 tile[32][33];
  int tx = threadIdx.x, ty = threadIdx.y;           // block (32,8)
  int c0 = blockIdx.x * 32, r0 = blockIdx.y * 32;
#pragma unroll
  for (int i = 0; i < 4; ++i)
    tile[ty + i * 8][tx] = in[(long)(r0 + ty + i * 8) * ld_in + col_off + c0 + tx];
  __syncthreads();
#pragma unroll
  for (int i = 0; i < 4; ++i)
    out[(long)(c0 + ty + i * 8) * R + r0 + tx] = tile[tx][ty + i * 8];
}

// ---------- RoPE on bf16 (strided input slice) -> packed bf16 ----------
__global__ void rope_bf16(const u16* __restrict__ in, const float* __restrict__ cosb,
                          const float* __restrict__ sinb, u16* __restrict__ out,
                          int H, int ld_in, int col_off, float scale) {
  int idx = blockIdx.x * blockDim.x + threadIdx.x;   // over S*H*64
  int j = idx & 63;
  int sh = idx >> 6;            // s*H + h
  int s = sh / H, h = sh - s * H;
  const u16* ip = in + (long)s * ld_in + col_off + h * HD;
  union { u32 u; u16 s2[2]; } v; v.u = *(const u32*)(ip + 2 * j);
  float q0 = bf2f(v.s2[0]), q1 = bf2f(v.s2[1]);
  float c = cosb[s * 64 + j], sn = sinb[s * 64 + j];
  union { u16 s2[2]; u32 u; } o;
  o.s2[0] = f2bf((q0 * c - q1 * sn) * scale);
  o.s2[1] = f2bf((q0 * sn + q1 * c) * scale);
  *(u32*)(out + (long)sh * HD + 2 * j) = o.u;
}

// ---------- pipelined GEMM: BM=256, BK=32, 4-deep LDS ring, 8 waves ----------
// ONE barrier + one counted vmcnt per K-tile (sync fixed-cost was the limiter:
// r3 evidence — BN=192 and BN=128 kernels had identical dur despite 1.5x FLOP
// difference, both with 4 barriers/K-tile).
// Ring safety with 1 barrier/K-tile:
//  WAR: stage(t+3) in tile t writes slot (t-1)&3; every wave exited tile t-1
//       through the end-of-(t-1) barrier, and each wave's ds_reads of t-1
//       completed before that barrier (consumed by MFMA via lgkm waits).
//  RAW: end-of-tile VMWAIT(N) (in-order DMA retirement) guarantees tile t+1
//       fully landed; the barrier publishes it to all waves.
// Within a K-tile, all ds_read->MFMA ordering is register-dependency; the
// compiler emits fine-grained lgkmcnt(N). Barriers are inline-asm ("memory"
// clobber pins memory ops inside the tile; no compiler vmcnt(0) drain).
#define BARRIER() asm volatile("s_barrier" ::: "memory")
#define WAIT_VM(N) asm volatile("s_waitcnt vmcnt(" #N ")" ::: "memory")

#define K_TILE(T, DO_STAGE, VMWAIT)                                               \
  {                                                                               \
    const u16* Ab_ = &lds[(T) & 3][0];                                            \
    const u16* Bb_ = &lds[(T) & 3][8192];                                         \
    bf16x8 bfr_[NF];                                                              \
    _Pragma("unroll")                                                             \
    for (int j = 0; j < NF; ++j) bfr_[j] = rdfrag(Bb_, wc * WCOLS + j * 16 + l15);\
    bf16x8 af0_[MFH];                                                             \
    _Pragma("unroll")                                                             \
    for (int i = 0; i < MFH; ++i) af0_[i] = rdfrag(Ab_, wr * MROWS + i * 16 + l15);\
    if (DO_STAGE) stageA((T) + 3);                                                \
    __builtin_amdgcn_s_setprio(1);                                                \
    _Pragma("unroll")                                                             \
    for (int i = 0; i < MFH; ++i)                                                 \
      _Pragma("unroll")                                                           \
      for (int j = 0; j < NF; ++j) acc[i][j] = mfma16(af0_[i], bfr_[j], acc[i][j]);\
    __builtin_amdgcn_s_setprio(0);                                                \
    bf16x8 af1_[MFH];                                                             \
    _Pragma("unroll")                                                             \
    for (int i = 0; i < MFH; ++i)                                                 \
      af1_[i] = rdfrag(Ab_, wr * MROWS + (MFH + i) * 16 + l15);                   \
    if (DO_STAGE) stageB((T) + 3);                                                \
    __builtin_amdgcn_s_setprio(1);                                                \
    _Pragma("unroll")                                                             \
    for (int i = 0; i < MFH; ++i)                                                 \
      _Pragma("unroll")                                                           \
      for (int j = 0; j < NF; ++j)                                                \
        acc[MFH + i][j] = mfma16(af1_[i], bfr_[j], acc[MFH + i][j]);              \
    __builtin_amdgcn_s_setprio(0);                                                \
    VMWAIT;                                                                       \
    BARRIER();                                                                    \
  }

// C(M,N) = A(M,K)bf16 @ Bt(N,K)^T.
// BN=192: waves 2Mx4N, per-wave 128x48 (QKV, grid 32x8 = 256 wgs = full fill).
// BN=128: waves 4Mx2N, per-wave 64x64  (proj, grid 32x8 = 256 wgs).
template <int BN, int WM, bool BF16OUT>
__global__ __launch_bounds__(512, 2) void gemm_pipe(
    const u16* __restrict__ A, const u16* __restrict__ Bt, void* __restrict__ Cv,
    int N, int K) {
  constexpr int WN = 8 / WM;
  constexpr int MROWS = 256 / WM;       // per-wave M rows
  constexpr int MF = MROWS / 16;        // m-frags per wave
  constexpr int MFH = MF / 2;           // m-frags per half
  constexpr int NF = BN / (WN * 16);    // n-frags per wave
  constexpr int WCOLS = NF * 16;        // per-wave N cols
  constexpr int BCH = BN * 4;           // real B 16B-chunks per tile
  constexpr int BISS = (BCH + 511) / 512;   // B loads per thread (w/ dup pad)
  constexpr int LDSU = (256 + BN) * 32; // u16 per ring slot

  __shared__ __attribute__((aligned(16))) u16 lds[4][LDSU];

  const int tid = threadIdx.x;
  const int lane = tid & 63;
  const int wave = tid >> 6;
  const int quad = lane >> 4, l15 = lane & 15;
  const int wr = wave / WN, wc = wave % WN;

  // T1: XCD-chunked swizzle (grid 256 = 8 XCDs x 32; bm = bid&7 -> one A-panel
  // (2 MB) resident per XCD L2)
  const int gx = gridDim.x;
  const int bid = blockIdx.y * gx + blockIdx.x;
  const int cpx = (gx * gridDim.y) >> 3;
  const int sw = (bid & 7) * cpx + (bid >> 3);
  const int bn = sw % gx, bm = sw / gx;

  const long arow = (long)bm * 256, brow = (long)bn * BN;
  const int NT = K >> 5;

  // chunk swizzle: LDS chunk cc of row holds src chunk cc ^ ((row>>1)&3)
  auto stageA = [&](int ts) {
    const int bs = ts & 3;
    const int k0 = ts * 32;
#pragma unroll
    for (int j = 0; j < 2; ++j) {
      int c = tid + j * 512;
      int row = c >> 2, cc = c & 3, cs = cc ^ ((row >> 1) & 3);
      async_load16(A + (arow + row) * (long)K + k0 + cs * 8,
                   (u16*)&lds[bs][0] + c * 8);
    }
  };
  // BN=192: chunks 512..767 are loaded twice (tid and tid+256) to the same LDS
  // dest with the same global data -> benign duplicate; keeps per-wave VMEM
  // issue count uniform so the vmcnt constants hold for every wave.
  auto stageB = [&](int ts) {
    const int bs = ts & 3;
    const int k0 = ts * 32;
#pragma unroll
    for (int j = 0; j < BISS; ++j) {
      int c = tid + j * 512;
      int cd = (c < BCH) ? c : c - 256;
      int row = cd >> 2, cc = cd & 3, cs = cc ^ ((row >> 1) & 3);
      async_load16(Bt + (brow + row) * (long)K + k0 + cs * 8,
                   (u16*)&lds[bs][8192] + cd * 8);
    }
  };
  auto rdfrag = [&](const u16* base, int row) -> bf16x8 {
    return *(const bf16x8*)(base + row * 32 + ((quad ^ ((row >> 1) & 3)) * 8));
  };

  f32x4 acc[MF][NF] = {};

  // prologue: stage tiles 0,1,2; drain so tile 0 landed (2 tiles in flight)
  stageA(0); stageB(0); stageA(1); stageB(1); stageA(2); stageB(2);
  if constexpr (BISS == 2) { WAIT_VM(8); } else { WAIT_VM(6); }
  BARRIER();

  int t = 0;
  for (; t < NT - 3; ++t) {
    if constexpr (BISS == 2) { K_TILE(t, true, WAIT_VM(8)); }
    else                     { K_TILE(t, true, WAIT_VM(6)); }
  }
  // tails: no more staging; tighten waits so tile t+1 is always landed
  if constexpr (BISS == 2) { K_TILE(t, false, WAIT_VM(4)); }
  else                     { K_TILE(t, false, WAIT_VM(3)); }
  ++t;
  K_TILE(t, false, WAIT_VM(0));
  ++t;
  K_TILE(t, false, ((void)0));

  // epilogue: C row from A (quad*4+r), col from B (l15)
#pragma unroll
  for (int i = 0; i < MF; ++i) {
    const long row = (long)bm * 256 + wr * MROWS + i * 16 + quad * 4;
#pragma unroll
    for (int j = 0; j < NF; ++j) {
      const int col = bn * BN + wc * WCOLS + j * 16 + l15;
      if constexpr (BF16OUT) {
        u16* C = (u16*)Cv;
#pragma unroll
        for (int r = 0; r < 4; ++r) C[(row + r) * N + col] = f2bf(acc[i][j][r]);
      } else {
        float* C = (float*)Cv;
#pragma unroll
        for (int r = 0; r < 4; ++r) C[(row + r) * N + col] = acc[i][j][r];
      }
    }
  }
}

// ---------- flash attention v2 ----------
// grid (16, HQ) = 512 blocks; 256 thr = 4 waves; q-tile 128 (wave owns 32 rows).
// Balanced (h,u) remap: linear b pairs with b+256 on the same CU (round-robin
// heuristic); u(b)+u(b+256)=15 so per-CU work is constant (34 KV-64 iters).
// KVBLK=64, double-buffered K/V; stage(t+1) issued BEFORE compute(t); the
// trailing __syncthreads (vmcnt0+lgkmcnt0+barrier) lands t+1 and republishes.
// WAR safe: buffer (t+1)&1 last read in iter t-1, before its trailing barrier.
// LDS: Ks 2x16KB + Vs 2x16KB + Pts 8KB = 72KB -> 2 blocks/CU.
#define NEG_INF -1e30f
__global__ __launch_bounds__(256, 2) void attn_fwd(
    const u16* __restrict__ Qb, const u16* __restrict__ Kb,
    const u16* __restrict__ Vt, u16* __restrict__ Ob) {
  __shared__ __attribute__((aligned(16))) u16 Ks[2][64 * 128];   // kpos-major
  __shared__ __attribute__((aligned(16))) u16 Vs[2][128 * 64];   // d-major (V^T)
  __shared__ __attribute__((aligned(16))) u16 Pts[4][16 * 64];   // per-wave P^T
  const int tid = threadIdx.x;
  const int lane = tid & 63, wave = tid >> 6;
  const int quad = lane >> 4, l15 = lane & 15;
  const int lin = blockIdx.y * gridDim.x + blockIdx.x;
  const int h = lin & 31;
  const int pp = (lin >> 5) & 7;
  const int u = (lin >> 8) ? 15 - pp : pp;     // q-tile index
  const int hk = h >> 2;
  const int swz = 2 * (l15 & 7);               // even XOR swizzle for Pt units
  const int nt = 2 * (u + 1);                  // KV-64 tiles

  // Q fragments as B-operand: qf[n][ks], qrow = u*128 + wave*32 + n*16 + l15
  bf16x8 qf[2][4];
#pragma unroll
  for (int n = 0; n < 2; ++n) {
    const u16* qrow = Qb + (long)(u * 128 + wave * 32 + n * 16 + l15) * (HQ * HD)
                      + h * HD + quad * 8;
#pragma unroll
    for (int ks = 0; ks < 4; ++ks) qf[n][ks] = *(const bf16x8*)(qrow + ks * 32);
  }

  // stage K (64 kpos rows x 128d, 16 chunks/row, ^row&15) and
  //       V^T (128 d rows x 64 kpos, 8 chunks/row, ^row&7) for tile t
  auto stage = [&](int t) {
    const int b = t & 1;
#pragma unroll
    for (int it = 0; it < 4; ++it) {
      int c = tid + it * 256;
      int row = c >> 4, cc = c & 15, cs = cc ^ (row & 15);
      async_load16(Kb + (long)(t * 64 + row) * (HK * HD) + hk * HD + cs * 8,
                   (u16*)&Ks[b][0] + c * 8);
    }
#pragma unroll
    for (int it = 0; it < 4; ++it) {
      int c = tid + it * 256;
      int row = c >> 3, cc = c & 7, cs = cc ^ (row & 7);
      async_load16(Vt + (long)(hk * HD + row) * S_LEN + t * 64 + cs * 8,
                   (u16*)&Vs[b][0] + c * 8);
    }
  };

  float m_run[2] = {NEG_INF, NEG_INF}, l_run[2] = {0.f, 0.f};
  f32x4 oacc[8][2] = {};

  stage(0);
  __syncthreads();

  for (int t = 0; t < nt; ++t) {
    const int cur = t & 1;
    if (t + 1 < nt) stage(t + 1);

    // skip waves whose rows are entirely above this KV tile (fully masked)
    if (t * 64 <= u * 128 + wave * 32 + 31) {
      // ---- S^T = K @ Q^T : sc[tj][n], row=kpos(quad*4+r), col=qrow(l15) ----
      f32x4 sc[4][2] = {};
      __builtin_amdgcn_s_setprio(1);
#pragma unroll
      for (int ks = 0; ks < 4; ++ks)
#pragma unroll
        for (int tj = 0; tj < 4; ++tj) {
          int row = tj * 16 + l15;
          bf16x8 kf = *(const bf16x8*)(&Ks[cur][0] + row * 128
                                       + (((ks * 4 + quad) ^ (row & 15)) * 8));
          sc[tj][0] = mfma16(kf, qf[0][ks], sc[tj][0]);
          sc[tj][1] = mfma16(kf, qf[1][ks], sc[tj][1]);
        }
      __builtin_amdgcn_s_setprio(0);

      // ---- online softmax (defer-max, THR=8) ----
      const bool diag = (t >= 2 * u);
      const int kbase = t * 64 - u * 128;
#pragma unroll
      for (int n = 0; n < 2; ++n) {
        int qloc = wave * 32 + n * 16 + l15;
        if (diag) {
#pragma unroll
          for (int tj = 0; tj < 4; ++tj)
#pragma unroll
            for (int r = 0; r < 4; ++r)
              if (kbase + tj * 16 + quad * 4 + r > qloc) sc[tj][n][r] = NEG_INF;
        }
        float m = NEG_INF;
#pragma unroll
        for (int tj = 0; tj < 4; ++tj)
#pragma unroll
          for (int r = 0; r < 4; ++r) m = fmaxf(m, sc[tj][n][r]);
        m = fmaxf(m, __shfl_xor(m, 16));
        m = fmaxf(m, __shfl_xor(m, 32));
        if (!__all(m - m_run[n] <= 8.0f)) {
          float mnew = fmaxf(m_run[n], m);
          float alpha = __expf(m_run[n] - mnew);
          m_run[n] = mnew;
          l_run[n] *= alpha;
#pragma unroll
          for (int tj = 0; tj < 8; ++tj) oacc[tj][n] *= alpha;
        }
        float rs = 0.f;
#pragma unroll
        for (int tj = 0; tj < 4; ++tj)
#pragma unroll
          for (int r = 0; r < 4; ++r) {
            float p = __expf(sc[tj][n][r] - m_run[n]);
            sc[tj][n][r] = p;
            rs += p;
          }
        rs += __shfl_xor(rs, 16);
        rs += __shfl_xor(rs, 32);
        l_run[n] += rs;
      }

      // ---- P^T -> per-wave LDS (b64 writes), read back as B frags (b128) ----
      u16* pw = &Pts[wave][0];
      bf16x8 pf0[2], pf1[2];
#pragma unroll
      for (int tj = 0; tj < 4; ++tj) {
        union { u32 w[2]; uint2 u2; } pk;
        pk.w[0] = pack2bf(sc[tj][0][0], sc[tj][0][1]);
        pk.w[1] = pack2bf(sc[tj][0][2], sc[tj][0][3]);
        *(uint2*)(pw + l15 * 64 + (((tj * 4 + quad) ^ swz) * 4)) = pk.u2;
      }
      __asm__ volatile("s_waitcnt lgkmcnt(0)" ::: "memory");
#pragma unroll
      for (int ks = 0; ks < 2; ++ks)
        pf0[ks] = *(const bf16x8*)(pw + l15 * 64 + (((ks * 8 + quad * 2) ^ swz) * 4));
      __asm__ volatile("s_waitcnt lgkmcnt(0)" ::: "memory");
#pragma unroll
      for (int tj = 0; tj < 4; ++tj) {
        union { u32 w[2]; uint2 u2; } pk;
        pk.w[0] = pack2bf(sc[tj][1][0], sc[tj][1][1]);
        pk.w[1] = pack2bf(sc[tj][1][2], sc[tj][1][3]);
        *(uint2*)(pw + l15 * 64 + (((tj * 4 + quad) ^ swz) * 4)) = pk.u2;
      }
      __asm__ volatile("s_waitcnt lgkmcnt(0)" ::: "memory");
#pragma unroll
      for (int ks = 0; ks < 2; ++ks)
        pf1[ks] = *(const bf16x8*)(pw + l15 * 64 + (((ks * 8 + quad * 2) ^ swz) * 4));

      // ---- O^T += V^T @ P^T ----
      __builtin_amdgcn_s_setprio(1);
#pragma unroll
      for (int ks = 0; ks < 2; ++ks)
#pragma unroll
        for (int tj = 0; tj < 8; ++tj) {
          int row = tj * 16 + l15;
          bf16x8 vf = *(const bf16x8*)(&Vs[cur][0] + row * 64
                                       + (((ks * 4 + quad) ^ (row & 7)) * 8));
          oacc[tj][0] = mfma16(vf, pf0[ks], oacc[tj][0]);
          oacc[tj][1] = mfma16(vf, pf1[ks], oacc[tj][1]);
        }
      __builtin_amdgcn_s_setprio(0);
    }

    __syncthreads();   // vmcnt(0): stage(t+1) landed; publishes to all waves
  }

  // ---- epilogue: O^T tile row=d(quad*4+r), col=qrow(l15); pack 4 bf16 ----
#pragma unroll
  for (int n = 0; n < 2; ++n) {
    float inv_l = 1.0f / l_run[n];
    long grow = u * 128 + wave * 32 + n * 16 + l15;
#pragma unroll
    for (int tj = 0; tj < 8; ++tj) {
      int gcol = h * HD + tj * 16 + quad * 4;
      union { u32 w[2]; uint2 u2; } pk;
      pk.w[0] = pack2bf(oacc[tj][n][0] * inv_l, oacc[tj][n][1] * inv_l);
      pk.w[1] = pack2bf(oacc[tj][n][2] * inv_l, oacc[tj][n][3] * inv_l);
      *(uint2*)(Ob + grow * (HQ * HD) + gcol) = pk.u2;
    }
  }
}

// ---------- host ----------
#define MB (1024L * 1024L)

extern "C" void kernel_launch(void* const* d_in, const int* in_sizes, int n_in,
                              void* d_out, int out_size, void* d_ws, size_t ws_size,
                              hipStream_t stream) {
  const float* x    = (const float*)d_in[0];
  const float* fcos = (const float*)d_in[1];
  const float* fsin = (const float*)d_in[2];
  const float* wq   = (const float*)d_in[3];
  const float* wk   = (const float*)d_in[4];
  const float* wv   = (const float*)d_in[5];
  const float* wo   = (const float*)d_in[6];
  float* out = (float*)d_out;

  char* ws = (char*)d_ws;
  u16* wt    = (u16*)(ws + 0 * MB);     // 48 MB: QKV weights^T (6144,4096); reused for wo^T
  u16* xb    = (u16*)(ws + 48 * MB);    // 16 MB
  u16* QKVb  = (u16*)(ws + 64 * MB);    // 24 MB: (S, 6144) bf16
  u16* Qb    = (u16*)(ws + 88 * MB);    // 16 MB
  u16* Kb    = (u16*)(ws + 104 * MB);   // 4 MB
  u16* Vt    = (u16*)(ws + 108 * MB);   // 4 MB
  u16* attnb = (u16*)(ws + 112 * MB);   // 16 MB

  const int M = S_LEN, D = D_MODEL;

  // x -> bf16
  cvt_f32_bf16<<<(M * D) / 1024, 256, 0, stream>>>(x, xb, M * D);

  // weights^T (concat rows: wq^T | wk^T | wv^T)
  transpose_f32_bf16<<<dim3(D / 32, D / 32), dim3(32, 8), 0, stream>>>(wq, wt, D, HQ * HD);
  transpose_f32_bf16<<<dim3((HK * HD) / 32, D / 32), dim3(32, 8), 0, stream>>>(
      wk, wt + (long)(HQ * HD) * D, D, HK * HD);
  transpose_f32_bf16<<<dim3((HK * HD) / 32, D / 32), dim3(32, 8), 0, stream>>>(
      wv, wt + (long)(HQ * HD + HK * HD) * D, D, HK * HD);

  // fused QKV projection -> bf16  (pipelined 256x192 GEMM, grid 32x8 = 256 wgs)
  gemm_pipe<192, 2, true><<<dim3(NQKV / 192, M / 256), 512, 0, stream>>>(
      xb, wt, QKVb, NQKV, D);

  // RoPE (scale folded into Q) from QKV slices
  rope_bf16<<<(M * HQ * 64) / 256, 256, 0, stream>>>(
      QKVb, fcos, fsin, Qb, HQ, NQKV, 0, 0.08838834764831845f);
  rope_bf16<<<(M * HK * 64) / 256, 256, 0, stream>>>(
      QKVb, fcos, fsin, Kb, HK, NQKV, HQ * HD, 1.0f);
  // V^T from QKV slice
  transpose_bf16<<<dim3((HK * HD) / 32, M / 32), dim3(32, 8), 0, stream>>>(
      QKVb, Vt, M, HK * HD, NQKV, HQ * HD + HK * HD);

  // flash attention
  attn_fwd<<<dim3(16, HQ), 256, 0, stream>>>(Qb, Kb, Vt, attnb);

  // out = attn @ wo  (pipelined 256x128 GEMM, grid 32x8 = 256 wgs)
  transpose_f32_bf16<<<dim3(D / 32, D / 32), dim3(32, 8), 0, stream>>>(wo, wt, HQ * HD, D);
  gemm_pipe<128, 4, false><<<dim3(D / 128, M / 256), 512, 0, stream>>>(
      attnb, wt, out, D, HQ * HD);
}